// Round 3
// baseline (648.927 us; speedup 1.0000x reference)
//
#include <hip/hip_runtime.h>

// ---------------------------------------------------------------------------
// SelfAttention fused pipeline — round 2.
//   B=8, L=1024, C=1024, H=16, D=64
// Tier 1 (ws >= 240 MiB): split-bf16 MFMA GEMMs + split-bf16 MFMA flash attn.
// Tier 2 (ws >= 144 MiB): split-bf16 MFMA GEMMs + fp32 flash attn.
// Tier 3 (else, needs 128 MiB): pure fp32 path.
//
// Tier-1 workspace layout:
//   qkv  fp32 [8192][3072]   @ 0..96 MiB     (dead after norm/v_split)
//   xh/xl bf16 [8192][1024]  @ 96/112 MiB    (reused as att_h/att_l)
//   qk_h/qk_l bf16 [8192][2048] @ 128/160    (cols 0..1023 q, 1024..2047 k)
//   vth/vtl bf16 [B,H,64,1024]  @ 192/208    (V transposed, hi/lo)
//   wqh/wql bf16 [3072][1024]   @ 224/230
//   wph/wpl bf16 [1024][1024]   @ 236/238    (total 240 MiB)
// ---------------------------------------------------------------------------

#define LN100 4.6051701859880914f

typedef __attribute__((ext_vector_type(8))) short short8;
typedef __attribute__((ext_vector_type(4))) float f32x4;

#define MFMA_BF16(a, b, c) __builtin_amdgcn_mfma_f32_16x16x32_bf16(a, b, c, 0, 0, 0)

__device__ __forceinline__ unsigned short f2bf(float f) {
  unsigned u = __float_as_uint(f);
  u += 0x7fffu + ((u >> 16) & 1u);          // RNE (no NaNs in this workload)
  return (unsigned short)(u >> 16);
}
__device__ __forceinline__ float bf2f(unsigned short h) {
  return __uint_as_float(((unsigned)h) << 16);
}

__device__ __forceinline__ float bias_sel0(const float* qb, const float* vb, int col) {
  if (col < 1024) return qb[col];
  if (col < 2048) return 0.0f;
  return vb[col - 2048];
}

#define G2L16(gp, lp) __builtin_amdgcn_global_load_lds( \
    (const __attribute__((address_space(1))) void*)(gp), \
    (__attribute__((address_space(3))) void*)(lp), 16, 0, 0)

// ---------------------------------------------------------------------------
// split fp32 -> (hi, lo) bf16 pair, 4 elems/thread
// ---------------------------------------------------------------------------
__global__ __launch_bounds__(256)
void split_f32_bf16(const float* __restrict__ in, unsigned short* __restrict__ hi,
                    unsigned short* __restrict__ lo, int n4)
{
  int i = blockIdx.x * blockDim.x + threadIdx.x;
  if (i >= n4) return;
  float4 v = ((const float4*)in)[i];
  ushort4 h, l;
  h.x = f2bf(v.x); l.x = f2bf(v.x - bf2f(h.x));
  h.y = f2bf(v.y); l.y = f2bf(v.y - bf2f(h.y));
  h.z = f2bf(v.z); l.z = f2bf(v.z - bf2f(h.z));
  h.w = f2bf(v.w); l.w = f2bf(v.w - bf2f(h.w));
  ((ushort4*)hi)[i] = h;
  ((ushort4*)lo)[i] = l;
}

// ---------------------------------------------------------------------------
// Split-bf16 MFMA GEMM:  C[m,n] = sum_k (Ah+Al)[m,k] * (Wh+Wl)[n,k] + bias(n)
// 128x128 tile, BK=32, 4 waves (2x2), 64x64 per wave, 16x16x32 bf16 MFMA.
// LDS rows = 128B: [Ah row 32bf16 | Al row 32bf16], chunk swizzle c^=(row&7)
// -> fragment ds_read_b128 is 2-way max (free). global_load_lds width 16
// with inverse-swizzled global source.
// ---------------------------------------------------------------------------
template <int MODE>
__global__ __launch_bounds__(256)
void gemm_nt_split(const unsigned short* __restrict__ Ah, const unsigned short* __restrict__ Al,
                   const unsigned short* __restrict__ Wh, const unsigned short* __restrict__ Wl,
                   const float* __restrict__ b0, const float* __restrict__ b1,
                   float* __restrict__ C, int M, int N, int K)
{
  __shared__ unsigned short sA[128 * 64];   // [128 rows][64 u16] = 16 KiB
  __shared__ unsigned short sW[128 * 64];

  const int tid  = threadIdx.x;
  const int lane = tid & 63;
  const int l15  = lane & 15, lg = lane >> 4;
  const int w    = tid >> 6;
  const int wr   = (w >> 1) << 6;
  const int wc   = (w & 1) << 6;
  const int m0   = blockIdx.y << 7;
  const int n0   = blockIdx.x << 7;

  f32x4 acc[4][4];
  #pragma unroll
  for (int i = 0; i < 4; ++i)
    #pragma unroll
    for (int j = 0; j < 4; ++j)
      acc[i][j] = (f32x4){0.f, 0.f, 0.f, 0.f};

  for (int k0 = 0; k0 < K; k0 += 32) {
    __syncthreads();
    #pragma unroll
    for (int u = 0; u < 4; ++u) {
      int idx = (u << 8) + tid;           // 0..1023 : 16B chunk id
      int row = idx >> 3;
      int c   = idx & 7;
      int s   = c ^ (row & 7);            // inverse swizzle on source
      size_t rbA = (size_t)(m0 + row) * K + k0;
      size_t rbW = (size_t)(n0 + row) * K + k0;
      const unsigned short* srcA = (s < 4) ? (Ah + rbA + (s << 3))
                                           : (Al + rbA + ((s - 4) << 3));
      const unsigned short* srcW = (s < 4) ? (Wh + rbW + (s << 3))
                                           : (Wl + rbW + ((s - 4) << 3));
      G2L16(srcA, sA + (idx << 3));
      G2L16(srcW, sW + (idx << 3));
    }
    __syncthreads();

    short8 ah[4], al[4];
    #pragma unroll
    for (int i = 0; i < 4; ++i) {
      int row = wr + (i << 4) + l15;
      ah[i] = *(const short8*)(sA + (row << 6) + ((lg       ^ (row & 7)) << 3));
      al[i] = *(const short8*)(sA + (row << 6) + (((4 + lg) ^ (row & 7)) << 3));
    }
    #pragma unroll
    for (int j = 0; j < 4; ++j) {
      int row = wc + (j << 4) + l15;
      short8 wh = *(const short8*)(sW + (row << 6) + ((lg       ^ (row & 7)) << 3));
      short8 wl = *(const short8*)(sW + (row << 6) + (((4 + lg) ^ (row & 7)) << 3));
      #pragma unroll
      for (int i = 0; i < 4; ++i) {
        acc[i][j] = MFMA_BF16(ah[i], wh, acc[i][j]);
        acc[i][j] = MFMA_BF16(ah[i], wl, acc[i][j]);
        acc[i][j] = MFMA_BF16(al[i], wh, acc[i][j]);
      }
    }
  }

  // epilogue: C/D layout col=lane&15, row=(lane>>4)*4+reg
  #pragma unroll
  for (int j = 0; j < 4; ++j) {
    int col = n0 + wc + (j << 4) + l15;
    float bb = (MODE == 0) ? bias_sel0(b0, b1, col) : b0[col];
    #pragma unroll
    for (int i = 0; i < 4; ++i) {
      int rbase = m0 + wr + (i << 4) + (lg << 2);
      #pragma unroll
      for (int r = 0; r < 4; ++r)
        C[(size_t)(rbase + r) * N + col] = acc[i][j][r] + bb;
    }
  }
}

// ---------------------------------------------------------------------------
// l2norm q,k -> split bf16 arrays qk_h/qk_l [8192][2048] (q | k), tier 1.
// ---------------------------------------------------------------------------
__global__ __launch_bounds__(256)
void qk_norm_split(const float* __restrict__ qkv, const float* __restrict__ scale_mul,
                   unsigned short* __restrict__ qk_h, unsigned short* __restrict__ qk_l)
{
  int wave = (blockIdx.x << 2) + (threadIdx.x >> 6);
  int lane = threadIdx.x & 63;
  int h  = wave & 15;
  int bl = wave >> 4;
  size_t base = (size_t)bl * 3072 + (h << 6) + lane;
  float q = qkv[base];
  float k = qkv[base + 1024];
  float sq = q * q, sk = k * k;
  #pragma unroll
  for (int off = 32; off; off >>= 1) {
    sq += __shfl_xor(sq, off);
    sk += __shfl_xor(sk, off);
  }
  float sm = __expf(fminf(scale_mul[h], LN100));
  q = q / fmaxf(sqrtf(sq), 1e-12f) * sm;
  k = k / fmaxf(sqrtf(sk), 1e-12f);
  size_t ob = (size_t)bl * 2048 + (h << 6) + lane;
  unsigned short qh = f2bf(q);
  qk_h[ob] = qh;          qk_l[ob] = f2bf(q - bf2f(qh));
  unsigned short kh = f2bf(k);
  qk_h[ob + 1024] = kh;   qk_l[ob + 1024] = f2bf(k - bf2f(kh));
}

// ---------------------------------------------------------------------------
// V -> transposed split bf16: vth/vtl [B,H,D=64,L=1024]. Block = (b,h,128-kv).
// ---------------------------------------------------------------------------
__global__ __launch_bounds__(256)
void v_split_t(const float* __restrict__ qkv, unsigned short* __restrict__ vth,
               unsigned short* __restrict__ vtl)
{
  __shared__ unsigned short Th[64][136];   // 272B rows (16B-aligned)
  __shared__ unsigned short Tl[64][136];
  const int tid = threadIdx.x;
  const int kc = blockIdx.x & 7;
  const int h  = (blockIdx.x >> 3) & 15;
  const int b  = blockIdx.x >> 7;
  const int kv0 = kc << 7;

  #pragma unroll
  for (int u = 0; u < 8; ++u) {
    int idx = (u << 8) + tid;          // 0..2047
    int kv  = idx >> 4;
    int d4  = (idx & 15) << 2;
    float4 v = *(const float4*)(qkv + (size_t)((b << 10) + kv0 + kv) * 3072
                                    + 2048 + (h << 6) + d4);
    float e[4] = {v.x, v.y, v.z, v.w};
    #pragma unroll
    for (int j = 0; j < 4; ++j) {
      unsigned short hb = f2bf(e[j]);
      Th[d4 + j][kv] = hb;
      Tl[d4 + j][kv] = f2bf(e[j] - bf2f(hb));
    }
  }
  __syncthreads();

  const size_t ob = ((size_t)((b << 4) + h) << 6) * 1024;   // row d stride 1024
  #pragma unroll
  for (int u = 0; u < 4; ++u) {
    int idx = (u << 8) + tid;          // 0..1023 : 16B chunks
    int d  = idx >> 4;
    int cc = idx & 15;
    short8 hv = *(const short8*)(&Th[d][cc << 3]);
    short8 lv = *(const short8*)(&Tl[d][cc << 3]);
    size_t go = ob + (size_t)d * 1024 + kv0 + (cc << 3);
    *(short8*)(vth + go) = hv;
    *(short8*)(vtl + go) = lv;
  }
}

// ---------------------------------------------------------------------------
// Split-bf16 MFMA flash attention.
// Block = (b,h,qtile 64 rows), 4 waves; wave w owns q rows 16w..16w+15.
// S = QK^T via mfma(q_frag, k_frag) -> C/D: col=kv(lane&15 +16j), row=q(lg*4+r).
// Online softmax per row (lane-local over j, then 16-lane butterfly).
// P -> LDS (swizzled, hi/lo) -> A-fragments for PV; V from pre-transposed vth/vtl.
// All LDS tiles: 64 rows x 128B, chunk swizzle c^=(row&7) -> <=2-way conflicts.
// ---------------------------------------------------------------------------
__global__ __launch_bounds__(256)
void attn_mfma(const unsigned short* __restrict__ qk_h, const unsigned short* __restrict__ qk_l,
               const unsigned short* __restrict__ vth, const unsigned short* __restrict__ vtl,
               const float* __restrict__ bias,
               unsigned short* __restrict__ oh, unsigned short* __restrict__ ol)
{
  __shared__ unsigned short sKh[4096], sKl[4096];
  __shared__ unsigned short sVh[4096], sVl[4096];
  __shared__ unsigned short sPh[4096], sPl[4096];

  const int tid  = threadIdx.x;
  const int lane = tid & 63;
  const int l15  = lane & 15, lg = lane >> 4;
  const int w    = tid >> 6;
  const int qt = blockIdx.x & 15;
  const int h  = (blockIdx.x >> 4) & 15;
  const int b  = blockIdx.x >> 8;      // same (h,qt) blocks are 256 apart -> same XCD
  const int q0 = qt << 6;

  // Q fragments (A-operand): row q = q0+16w+l15, d-chunk lg*8 + ks*32
  short8 qh[2], qlo[2];
  {
    size_t rb = ((size_t)((b << 10) + q0 + (w << 4) + l15)) * 2048 + (h << 6) + (lg << 3);
    qh[0]  = *(const short8*)(qk_h + rb);
    qh[1]  = *(const short8*)(qk_h + rb + 32);
    qlo[0] = *(const short8*)(qk_l + rb);
    qlo[1] = *(const short8*)(qk_l + rb + 32);
  }

  f32x4 ao[4];
  #pragma unroll
  for (int j = 0; j < 4; ++j) ao[j] = (f32x4){0.f, 0.f, 0.f, 0.f};
  float mr[4], lr[4];
  #pragma unroll
  for (int r = 0; r < 4; ++r) { mr[r] = -3.0e38f; lr[r] = 0.0f; }

  const unsigned short* kh_base = qk_h + 1024 + (h << 6);
  const unsigned short* kl_base = qk_l + 1024 + (h << 6);
  const size_t vbase = ((size_t)((b << 4) + h)) * 65536;   // 64*1024

  for (int kv0 = 0; kv0 < 1024; kv0 += 64) {
    __syncthreads();
    #pragma unroll
    for (int u = 0; u < 2; ++u) {
      int idx = (u << 8) + tid;        // 0..511
      int r = idx >> 3, c = idx & 7;
      int s = c ^ (r & 7);
      size_t krow = (size_t)((b << 10) + kv0 + r) * 2048 + (s << 3);
      size_t vrow = vbase + (size_t)r * 1024 + kv0 + (s << 3);
      G2L16(kh_base + krow, sKh + (idx << 3));
      G2L16(kl_base + krow, sKl + (idx << 3));
      G2L16(vth + vrow,     sVh + (idx << 3));
      G2L16(vtl + vrow,     sVl + (idx << 3));
    }
    __syncthreads();

    // ---- S = Q.K^T : 4 kv-col fragments ----
    f32x4 sv[4];
    #pragma unroll
    for (int j = 0; j < 4; ++j) {
      f32x4 a = (f32x4){0.f, 0.f, 0.f, 0.f};
      #pragma unroll
      for (int ks = 0; ks < 2; ++ks) {
        int row = (j << 4) + l15;                 // kv row in tile
        int c   = (lg + (ks << 2)) ^ (row & 7);
        short8 kh = *(const short8*)(sKh + (row << 6) + (c << 3));
        short8 kl = *(const short8*)(sKl + (row << 6) + (c << 3));
        a = MFMA_BF16(qh[ks], kh, a);
        a = MFMA_BF16(qh[ks], kl, a);
        a = MFMA_BF16(qlo[ks], kh, a);
      }
      sv[j] = a;
    }

    // ---- bias + online softmax (row q = q0+16w+lg*4+r) ----
    float p[4][4], alpha[4];
    #pragma unroll
    for (int r = 0; r < 4; ++r) {
      int qrow = q0 + (w << 4) + (lg << 2) + r;
      const float* bp = bias + ((size_t)h << 20) + (size_t)qrow * 1024 + kv0 + l15;
      float s0 = sv[0][r] + bp[0];
      float s1 = sv[1][r] + bp[16];
      float s2 = sv[2][r] + bp[32];
      float s3 = sv[3][r] + bp[48];
      float mx = fmaxf(fmaxf(s0, s1), fmaxf(s2, s3));
      #pragma unroll
      for (int o = 1; o < 16; o <<= 1) mx = fmaxf(mx, __shfl_xor(mx, o));
      float mn = fmaxf(mr[r], mx);
      alpha[r] = __expf(mr[r] - mn);
      p[r][0] = __expf(s0 - mn); p[r][1] = __expf(s1 - mn);
      p[r][2] = __expf(s2 - mn); p[r][3] = __expf(s3 - mn);
      float rs = p[r][0] + p[r][1] + p[r][2] + p[r][3];
      #pragma unroll
      for (int o = 1; o < 16; o <<= 1) rs += __shfl_xor(rs, o);
      lr[r] = lr[r] * alpha[r] + rs;
      mr[r] = mn;
    }

    // rescale O
    #pragma unroll
    for (int jd = 0; jd < 4; ++jd)
      #pragma unroll
      for (int r = 0; r < 4; ++r)
        ao[jd][r] *= alpha[r];

    // ---- write P (hi/lo) to LDS in swizzled layout ----
    #pragma unroll
    for (int r = 0; r < 4; ++r) {
      int q2 = (w << 4) + (lg << 2) + r;
      #pragma unroll
      for (int j = 0; j < 4; ++j) {
        unsigned short hb = f2bf(p[r][j]);
        unsigned short lb = f2bf(p[r][j] - bf2f(hb));
        int c = ((j << 1) + (l15 >> 3)) ^ (q2 & 7);
        int e = (q2 << 6) + (c << 3) + (l15 & 7);
        sPh[e] = hb;
        sPl[e] = lb;
      }
    }
    // own-wave strip only -> no barrier needed (lgkmcnt ordering within wave)

    // ---- O += P.V ----
    #pragma unroll
    for (int ks = 0; ks < 2; ++ks) {
      int prow = (w << 4) + l15;
      int pc   = (lg + (ks << 2)) ^ (prow & 7);
      short8 ph = *(const short8*)(sPh + (prow << 6) + (pc << 3));
      short8 pl = *(const short8*)(sPl + (prow << 6) + (pc << 3));
      #pragma unroll
      for (int jd = 0; jd < 4; ++jd) {
        int vrow = (jd << 4) + l15;               // d row in Vt tile
        int vc   = (lg + (ks << 2)) ^ (vrow & 7);
        short8 vh = *(const short8*)(sVh + (vrow << 6) + (vc << 3));
        short8 vl = *(const short8*)(sVl + (vrow << 6) + (vc << 3));
        ao[jd] = MFMA_BF16(ph, vh, ao[jd]);
        ao[jd] = MFMA_BF16(ph, vl, ao[jd]);
        ao[jd] = MFMA_BF16(pl, vh, ao[jd]);
      }
    }
  }

  // epilogue: O /= l ; write split bf16 att [B,L,C]
  #pragma unroll
  for (int r = 0; r < 4; ++r) {
    float inv = 1.0f / lr[r];
    size_t orow = ((size_t)((b << 10) + q0 + (w << 4) + (lg << 2) + r)) * 1024
                + (h << 6) + l15;
    #pragma unroll
    for (int jd = 0; jd < 4; ++jd) {
      float v = ao[jd][r] * inv;
      unsigned short hb = f2bf(v);
      oh[orow + (jd << 4)] = hb;
      ol[orow + (jd << 4)] = f2bf(v - bf2f(hb));
    }
  }
}

// ---------------------------------------------------------------------------
// fp32 fallback GEMM
// ---------------------------------------------------------------------------
template <int MODE>
__global__ __launch_bounds__(256)
void gemm_nt(const float* __restrict__ A, const float* __restrict__ Bw,
             const float* __restrict__ b0, const float* __restrict__ b1,
             float* __restrict__ C, int M, int N, int K)
{
  __shared__ float As[32][132];
  __shared__ float Bs[32][132];
  const int tid = threadIdx.x;
  const int tx = tid & 15, ty = tid >> 4;
  const int m0 = blockIdx.y << 7;
  const int n0 = blockIdx.x << 7;

  float acc[8][8];
  #pragma unroll
  for (int i = 0; i < 8; ++i)
    #pragma unroll
    for (int j = 0; j < 8; ++j) acc[i][j] = 0.0f;

  for (int k0 = 0; k0 < K; k0 += 32) {
    #pragma unroll
    for (int u = 0; u < 4; ++u) {
      int f   = tid + (u << 8);
      int row = f >> 3;
      int kk  = (f & 7) << 2;
      float4 av = *(const float4*)(A  + (size_t)(m0 + row) * K + k0 + kk);
      As[kk + 0][row] = av.x; As[kk + 1][row] = av.y;
      As[kk + 2][row] = av.z; As[kk + 3][row] = av.w;
      float4 bv = *(const float4*)(Bw + (size_t)(n0 + row) * K + k0 + kk);
      Bs[kk + 0][row] = bv.x; Bs[kk + 1][row] = bv.y;
      Bs[kk + 2][row] = bv.z; Bs[kk + 3][row] = bv.w;
    }
    __syncthreads();
    #pragma unroll
    for (int kk = 0; kk < 32; ++kk) {
      float a[8], b[8];
      *(float4*)(a)     = *(const float4*)(&As[kk][(ty << 3)]);
      *(float4*)(a + 4) = *(const float4*)(&As[kk][(ty << 3) + 4]);
      *(float4*)(b)     = *(const float4*)(&Bs[kk][(tx << 3)]);
      *(float4*)(b + 4) = *(const float4*)(&Bs[kk][(tx << 3) + 4]);
      #pragma unroll
      for (int i = 0; i < 8; ++i)
        #pragma unroll
        for (int j = 0; j < 8; ++j)
          acc[i][j] = fmaf(a[i], b[j], acc[i][j]);
    }
    __syncthreads();
  }

  #pragma unroll
  for (int i = 0; i < 8; ++i) {
    int row = m0 + (ty << 3) + i;
    #pragma unroll
    for (int j4 = 0; j4 < 2; ++j4) {
      int col = n0 + (tx << 3) + (j4 << 2);
      float4 r;
      float bb[4];
      #pragma unroll
      for (int j = 0; j < 4; ++j)
        bb[j] = (MODE == 0) ? bias_sel0(b0, b1, col + j) : b0[col + j];
      r.x = acc[i][j4 * 4 + 0] + bb[0];
      r.y = acc[i][j4 * 4 + 1] + bb[1];
      r.z = acc[i][j4 * 4 + 2] + bb[2];
      r.w = acc[i][j4 * 4 + 3] + bb[3];
      *(float4*)(C + (size_t)row * N + col) = r;
    }
  }
}

// ---------------------------------------------------------------------------
// fp32 in-place qk norm (tiers 2/3)
// ---------------------------------------------------------------------------
__global__ __launch_bounds__(256)
void qk_norm(float* __restrict__ qkv, const float* __restrict__ scale_mul)
{
  int wave = (blockIdx.x << 2) + (threadIdx.x >> 6);
  int lane = threadIdx.x & 63;
  int h  = wave & 15;
  int bl = wave >> 4;
  size_t base = (size_t)bl * 3072 + (h << 6) + lane;
  float q = qkv[base];
  float k = qkv[base + 1024];
  float sq = q * q, sk = k * k;
  #pragma unroll
  for (int off = 32; off; off >>= 1) {
    sq += __shfl_xor(sq, off);
    sk += __shfl_xor(sk, off);
  }
  float sm = __expf(fminf(scale_mul[h], LN100));
  q = q / fmaxf(sqrtf(sq), 1e-12f) * sm;
  k = k / fmaxf(sqrtf(sk), 1e-12f);
  qkv[base]        = q;
  qkv[base + 1024] = k;
}

// ---------------------------------------------------------------------------
// fp32 flash attention (tiers 2/3). OUTMODE 0: fp32 out; 1: split bf16 out.
// ---------------------------------------------------------------------------
#define SW(r, c4) ((((c4) ^ ((r) >> 2)) & 15) << 2)

template <int OUTMODE>
__global__ __launch_bounds__(256)
void attn_fwd(const float* __restrict__ qkv, const float* __restrict__ bias,
              float* __restrict__ aout,
              unsigned short* __restrict__ ah, unsigned short* __restrict__ al)
{
  __shared__ float Qs[64][64];
  __shared__ float Ks[64][64];
  __shared__ float Vs[64][64];
  __shared__ float Ps[64][64];

  const int tid = threadIdx.x;
  const int tx = tid & 15, ty = tid >> 4;
  const int qt = blockIdx.x & 15;
  const int h  = (blockIdx.x >> 4) & 15;
  const int b  = blockIdx.x >> 8;
  const int q0 = qt << 6;

  #pragma unroll
  for (int u = 0; u < 4; ++u) {
    int f = tid + (u << 8);
    int r = f >> 4, c4 = f & 15;
    float4 v = *(const float4*)(qkv + (size_t)(b * 1024 + q0 + r) * 3072 + (h << 6) + (c4 << 2));
    *(float4*)(&Qs[r][SW(r, c4)]) = v;
  }

  float o[4][4];
  float mr[4], lr[4];
  #pragma unroll
  for (int i = 0; i < 4; ++i) {
    mr[i] = -3.0e38f; lr[i] = 0.0f;
    #pragma unroll
    for (int j = 0; j < 4; ++j) o[i][j] = 0.0f;
  }

  for (int kv0 = 0; kv0 < 1024; kv0 += 64) {
    __syncthreads();
    #pragma unroll
    for (int u = 0; u < 4; ++u) {
      int f = tid + (u << 8);
      int r = f >> 4, c4 = f & 15;
      size_t gb = (size_t)(b * 1024 + kv0 + r) * 3072 + (h << 6) + (c4 << 2);
      *(float4*)(&Ks[r][SW(r, c4)]) = *(const float4*)(qkv + gb + 1024);
      *(float4*)(&Vs[r][SW(r, c4)]) = *(const float4*)(qkv + gb + 2048);
    }
    __syncthreads();

    float s[4][4];
    #pragma unroll
    for (int i = 0; i < 4; ++i)
      #pragma unroll
      for (int j = 0; j < 4; ++j) s[i][j] = 0.0f;

    #pragma unroll 4
    for (int d4 = 0; d4 < 16; ++d4) {
      float4 qv[4], kv[4];
      #pragma unroll
      for (int i = 0; i < 4; ++i)
        qv[i] = *(const float4*)(&Qs[(ty << 2) + i][SW((ty << 2) + i, d4)]);
      #pragma unroll
      for (int j = 0; j < 4; ++j)
        kv[j] = *(const float4*)(&Ks[(tx << 2) + j][SW((tx << 2) + j, d4)]);
      #pragma unroll
      for (int i = 0; i < 4; ++i)
        #pragma unroll
        for (int j = 0; j < 4; ++j)
          s[i][j] += qv[i].x * kv[j].x + qv[i].y * kv[j].y +
                     qv[i].z * kv[j].z + qv[i].w * kv[j].w;
    }

    float p[4][4];
    #pragma unroll
    for (int i = 0; i < 4; ++i) {
      float4 bv = *(const float4*)(bias + (size_t)((h << 10) + q0 + (ty << 2) + i) * 1024
                                        + kv0 + (tx << 2));
      s[i][0] += bv.x; s[i][1] += bv.y; s[i][2] += bv.z; s[i][3] += bv.w;
      float mx = fmaxf(fmaxf(s[i][0], s[i][1]), fmaxf(s[i][2], s[i][3]));
      #pragma unroll
      for (int off = 1; off < 16; off <<= 1) mx = fmaxf(mx, __shfl_xor(mx, off));
      float mn = fmaxf(mr[i], mx);
      float alp = __expf(mr[i] - mn);
      float rs = 0.0f;
      #pragma unroll
      for (int j = 0; j < 4; ++j) { p[i][j] = __expf(s[i][j] - mn); rs += p[i][j]; }
      #pragma unroll
      for (int off = 1; off < 16; off <<= 1) rs += __shfl_xor(rs, off);
      lr[i] = lr[i] * alp + rs;
      mr[i] = mn;
      #pragma unroll
      for (int j = 0; j < 4; ++j) o[i][j] *= alp;
    }

    #pragma unroll
    for (int jj = 0; jj < 4; ++jj)
      #pragma unroll
      for (int i = 0; i < 4; ++i)
        Ps[(tx << 2) + jj][SW((tx << 2) + jj, ty) + i] = p[i][jj];
    __syncthreads();

    #pragma unroll 8
    for (int j = 0; j < 64; ++j) {
      float4 pv = *(const float4*)(&Ps[j][SW(j, ty)]);
      float4 vv = *(const float4*)(&Vs[j][SW(j, tx)]);
      o[0][0] += pv.x * vv.x; o[0][1] += pv.x * vv.y; o[0][2] += pv.x * vv.z; o[0][3] += pv.x * vv.w;
      o[1][0] += pv.y * vv.x; o[1][1] += pv.y * vv.y; o[1][2] += pv.y * vv.z; o[1][3] += pv.y * vv.w;
      o[2][0] += pv.z * vv.x; o[2][1] += pv.z * vv.y; o[2][2] += pv.z * vv.z; o[2][3] += pv.z * vv.w;
      o[3][0] += pv.w * vv.x; o[3][1] += pv.w * vv.y; o[3][2] += pv.w * vv.z; o[3][3] += pv.w * vv.w;
    }
  }

  #pragma unroll
  for (int i = 0; i < 4; ++i) {
    float inv = 1.0f / lr[i];
    float v0 = o[i][0] * inv, v1 = o[i][1] * inv, v2 = o[i][2] * inv, v3 = o[i][3] * inv;
    if (OUTMODE == 0) {
      float4 r; r.x = v0; r.y = v1; r.z = v2; r.w = v3;
      *(float4*)(aout + (size_t)(b * 1024 + q0 + (ty << 2) + i) * 1024 + (h << 6) + (tx << 2)) = r;
    } else {
      ushort4 hh, ll;
      hh.x = f2bf(v0); ll.x = f2bf(v0 - bf2f(hh.x));
      hh.y = f2bf(v1); ll.y = f2bf(v1 - bf2f(hh.y));
      hh.z = f2bf(v2); ll.z = f2bf(v2 - bf2f(hh.z));
      hh.w = f2bf(v3); ll.w = f2bf(v3 - bf2f(hh.w));
      size_t idx = (size_t)(b * 1024 + q0 + (ty << 2) + i) * 256 + (h << 4) + tx;
      ((ushort4*)ah)[idx] = hh;
      ((ushort4*)al)[idx] = ll;
    }
  }
}

// ---------------------------------------------------------------------------
extern "C" void kernel_launch(void* const* d_in, const int* in_sizes, int n_in,
                              void* d_out, int out_size, void* d_ws, size_t ws_size,
                              hipStream_t stream) {
  const float* x         = (const float*)d_in[0];
  const float* attn_bias = (const float*)d_in[1];
  const float* w_qkv     = (const float*)d_in[2];
  const float* q_bias    = (const float*)d_in[3];
  const float* v_bias    = (const float*)d_in[4];
  const float* scale_mul = (const float*)d_in[5];
  const float* w_proj    = (const float*)d_in[6];
  const float* b_proj    = (const float*)d_in[7];
  float* out = (float*)d_out;

  const size_t MiB = 1024 * 1024;
  char* ws = (char*)d_ws;
  dim3 blk(256);

  if (ws_size >= 240 * MiB) {
    // ---- tier 1: full MFMA path ----
    float*          qkv = (float*)ws;
    unsigned short* xh  = (unsigned short*)(ws + 96  * MiB);  // -> att_h
    unsigned short* xl  = (unsigned short*)(ws + 112 * MiB);  // -> att_l
    unsigned short* qkh = (unsigned short*)(ws + 128 * MiB);
    unsigned short* qkl = (unsigned short*)(ws + 160 * MiB);
    unsigned short* vth = (unsigned short*)(ws + 192 * MiB);
    unsigned short* vtl = (unsigned short*)(ws + 208 * MiB);
    unsigned short* wqh = (unsigned short*)(ws + 224 * MiB);
    unsigned short* wql = (unsigned short*)(ws + 230 * MiB);
    unsigned short* wph = (unsigned short*)(ws + 236 * MiB);
    unsigned short* wpl = (unsigned short*)(ws + 238 * MiB);

    split_f32_bf16<<<dim3(8192), blk, 0, stream>>>(x,      xh,  xl,  2097152);
    split_f32_bf16<<<dim3(3072), blk, 0, stream>>>(w_qkv,  wqh, wql, 786432);
    split_f32_bf16<<<dim3(1024), blk, 0, stream>>>(w_proj, wph, wpl, 262144);

    gemm_nt_split<0><<<dim3(24, 64), blk, 0, stream>>>(xh, xl, wqh, wql,
        q_bias, v_bias, qkv, 8192, 3072, 1024);
    qk_norm_split<<<dim3(32768), blk, 0, stream>>>(qkv, scale_mul, qkh, qkl);
    v_split_t<<<dim3(1024), blk, 0, stream>>>(qkv, vth, vtl);
    attn_mfma<<<dim3(2048), blk, 0, stream>>>(qkh, qkl, vth, vtl, attn_bias, xh, xl);
    gemm_nt_split<1><<<dim3(8, 64), blk, 0, stream>>>(xh, xl, wph, wpl,
        b_proj, nullptr, out, 8192, 1024, 1024);
  } else if (ws_size >= 144 * MiB) {
    // ---- tier 2: MFMA GEMMs + fp32 attention ----
    float*          qkv = (float*)ws;
    unsigned short* xh  = (unsigned short*)(ws + 96  * MiB);
    unsigned short* xl  = (unsigned short*)(ws + 112 * MiB);
    unsigned short* wqh = (unsigned short*)(ws + 128 * MiB);
    unsigned short* wql = (unsigned short*)(ws + 134 * MiB);
    unsigned short* wph = (unsigned short*)(ws + 140 * MiB);
    unsigned short* wpl = (unsigned short*)(ws + 142 * MiB);

    split_f32_bf16<<<dim3(8192), blk, 0, stream>>>(x,      xh,  xl,  2097152);
    split_f32_bf16<<<dim3(3072), blk, 0, stream>>>(w_qkv,  wqh, wql, 786432);
    split_f32_bf16<<<dim3(1024), blk, 0, stream>>>(w_proj, wph, wpl, 262144);

    gemm_nt_split<0><<<dim3(24, 64), blk, 0, stream>>>(xh, xl, wqh, wql,
        q_bias, v_bias, qkv, 8192, 3072, 1024);
    qk_norm<<<dim3(32768), blk, 0, stream>>>(qkv, scale_mul);
    attn_fwd<1><<<dim3(2048), blk, 0, stream>>>(qkv, attn_bias, nullptr, xh, xl);
    gemm_nt_split<1><<<dim3(8, 64), blk, 0, stream>>>(xh, xl, wph, wpl,
        b_proj, nullptr, out, 8192, 1024, 1024);
  } else {
    // ---- tier 3: pure fp32 ----
    float* qkv = (float*)ws;
    float* att = qkv + (size_t)8192 * 3072;
    gemm_nt<0><<<dim3(24, 64), blk, 0, stream>>>(x, w_qkv, q_bias, v_bias, qkv, 8192, 3072, 1024);
    qk_norm<<<dim3(32768), blk, 0, stream>>>(qkv, scale_mul);
    attn_fwd<0><<<dim3(2048), blk, 0, stream>>>(qkv, attn_bias, att, nullptr, nullptr);
    gemm_nt<1><<<dim3(8, 64), blk, 0, stream>>>(att, w_proj, b_proj, nullptr, out, 8192, 1024, 1024);
  }
}

// Round 5
// 602.262 us; speedup vs baseline: 1.0775x; 1.0775x over previous
//
#include <hip/hip_runtime.h>

// ---------------------------------------------------------------------------
// SelfAttention fused pipeline — round 4.
//   B=8, L=1024, C=1024, H=16, D=64
// Tier 1 (ws >= 240 MiB): split-bf16 MFMA GEMMs + split-bf16 MFMA flash attn
//   (QBLK=128). gemm1 now emits V directly as transposed split bf16 from its
//   epilogue (v_split_t kernel eliminated).
// Tier 2 (ws >= 144 MiB): split-bf16 MFMA GEMMs + fp32 flash attn.
// Tier 3 (else, needs 128 MiB): pure fp32 path.
// ---------------------------------------------------------------------------

#define LN100 4.6051701859880914f

typedef __attribute__((ext_vector_type(8))) short short8;
typedef __attribute__((ext_vector_type(4))) float f32x4;

#define MFMA_BF16(a, b, c) __builtin_amdgcn_mfma_f32_16x16x32_bf16(a, b, c, 0, 0, 0)

__device__ __forceinline__ unsigned short f2bf(float f) {
  unsigned u = __float_as_uint(f);
  u += 0x7fffu + ((u >> 16) & 1u);          // RNE (no NaNs in this workload)
  return (unsigned short)(u >> 16);
}
__device__ __forceinline__ float bf2f(unsigned short h) {
  return __uint_as_float(((unsigned)h) << 16);
}

__device__ __forceinline__ float bias_sel0(const float* qb, const float* vb, int col) {
  if (col < 1024) return qb[col];
  if (col < 2048) return 0.0f;
  return vb[col - 2048];
}

#define G2L16(gp, lp) __builtin_amdgcn_global_load_lds( \
    (const __attribute__((address_space(1))) void*)(gp), \
    (__attribute__((address_space(3))) void*)(lp), 16, 0, 0)

// ---------------------------------------------------------------------------
// split fp32 -> (hi, lo) bf16 pair, 4 elems/thread
// ---------------------------------------------------------------------------
__global__ __launch_bounds__(256)
void split_f32_bf16(const float* __restrict__ in, unsigned short* __restrict__ hi,
                    unsigned short* __restrict__ lo, int n4)
{
  int i = blockIdx.x * blockDim.x + threadIdx.x;
  if (i >= n4) return;
  float4 v = ((const float4*)in)[i];
  ushort4 h, l;
  h.x = f2bf(v.x); l.x = f2bf(v.x - bf2f(h.x));
  h.y = f2bf(v.y); l.y = f2bf(v.y - bf2f(h.y));
  h.z = f2bf(v.z); l.z = f2bf(v.z - bf2f(h.z));
  h.w = f2bf(v.w); l.w = f2bf(v.w - bf2f(h.w));
  ((ushort4*)hi)[i] = h;
  ((ushort4*)lo)[i] = l;
}

// ---------------------------------------------------------------------------
// Split-bf16 MFMA GEMM:  C[m,n] = sum_k (Ah+Al)[m,k] * (Wh+Wl)[n,k] + bias(n)
// 128x128 tile, BK=32, 4 waves (2x2), 64x64 per wave, 16x16x32 bf16 MFMA.
// MODE 0: qkv GEMM, tier-1 — q/k cols -> fp32 C; V cols (>=2048) -> directly
//         transposed split bf16 vth/vtl [B,H,64,1024] (+v_bias).
// MODE 1: proj GEMM (b0 bias, fp32 C).
// MODE 2: qkv GEMM, plain fp32 C for all 3072 cols (tier 2).
// ---------------------------------------------------------------------------
template <int MODE>
__global__ __launch_bounds__(256)
void gemm_nt_split(const unsigned short* __restrict__ Ah, const unsigned short* __restrict__ Al,
                   const unsigned short* __restrict__ Wh, const unsigned short* __restrict__ Wl,
                   const float* __restrict__ b0, const float* __restrict__ b1,
                   float* __restrict__ C,
                   unsigned short* __restrict__ vth, unsigned short* __restrict__ vtl,
                   int M, int N, int K)
{
  __shared__ unsigned short sA[128 * 64];   // [128 rows][64 u16] = 16 KiB
  __shared__ unsigned short sW[128 * 64];

  const int tid  = threadIdx.x;
  const int lane = tid & 63;
  const int l15  = lane & 15, lg = lane >> 4;
  const int w    = tid >> 6;
  const int wr   = (w >> 1) << 6;
  const int wc   = (w & 1) << 6;
  const int m0   = blockIdx.y << 7;
  const int n0   = blockIdx.x << 7;

  f32x4 acc[4][4];
  #pragma unroll
  for (int i = 0; i < 4; ++i)
    #pragma unroll
    for (int j = 0; j < 4; ++j)
      acc[i][j] = (f32x4){0.f, 0.f, 0.f, 0.f};

  for (int k0 = 0; k0 < K; k0 += 32) {
    __syncthreads();
    #pragma unroll
    for (int u = 0; u < 4; ++u) {
      int idx = (u << 8) + tid;           // 0..1023 : 16B chunk id
      int row = idx >> 3;
      int c   = idx & 7;
      int s   = c ^ (row & 7);            // inverse swizzle on source
      size_t rbA = (size_t)(m0 + row) * K + k0;
      size_t rbW = (size_t)(n0 + row) * K + k0;
      const unsigned short* srcA = (s < 4) ? (Ah + rbA + (s << 3))
                                           : (Al + rbA + ((s - 4) << 3));
      const unsigned short* srcW = (s < 4) ? (Wh + rbW + (s << 3))
                                           : (Wl + rbW + ((s - 4) << 3));
      G2L16(srcA, sA + (idx << 3));
      G2L16(srcW, sW + (idx << 3));
    }
    __syncthreads();

    short8 ah[4], al[4];
    #pragma unroll
    for (int i = 0; i < 4; ++i) {
      int row = wr + (i << 4) + l15;
      ah[i] = *(const short8*)(sA + (row << 6) + ((lg       ^ (row & 7)) << 3));
      al[i] = *(const short8*)(sA + (row << 6) + (((4 + lg) ^ (row & 7)) << 3));
    }
    #pragma unroll
    for (int j = 0; j < 4; ++j) {
      int row = wc + (j << 4) + l15;
      short8 wh = *(const short8*)(sW + (row << 6) + ((lg       ^ (row & 7)) << 3));
      short8 wl = *(const short8*)(sW + (row << 6) + (((4 + lg) ^ (row & 7)) << 3));
      #pragma unroll
      for (int i = 0; i < 4; ++i) {
        acc[i][j] = MFMA_BF16(ah[i], wh, acc[i][j]);
        acc[i][j] = MFMA_BF16(ah[i], wl, acc[i][j]);
        acc[i][j] = MFMA_BF16(al[i], wh, acc[i][j]);
      }
    }
  }

  // epilogue: C/D layout col=lane&15, row=(lane>>4)*4+reg
  if (MODE == 0 && n0 >= 2048) {
    // V third: write transposed split bf16 directly: vth[((b*16+h)*64+d)*1024+l]
    #pragma unroll
    for (int j = 0; j < 4; ++j) {
      int col = n0 + wc + (j << 4) + l15;          // 2048..3071
      int d   = col - 2048;
      int hh  = d >> 6, dd = d & 63;
      float bb = b1[d];                            // v_bias
      #pragma unroll
      for (int i = 0; i < 4; ++i) {
        int row  = m0 + wr + (i << 4) + (lg << 2); // rows row..row+3, same batch
        int bidx = row >> 10;
        int l    = row & 1023;
        size_t obase = ((((size_t)bidx << 4) + hh) << 6) + dd;
        obase = obase * 1024 + l;
        ushort4 hv, lv;
        float v0 = acc[i][j][0] + bb;
        float v1 = acc[i][j][1] + bb;
        float v2 = acc[i][j][2] + bb;
        float v3 = acc[i][j][3] + bb;
        hv.x = f2bf(v0); lv.x = f2bf(v0 - bf2f(hv.x));
        hv.y = f2bf(v1); lv.y = f2bf(v1 - bf2f(hv.y));
        hv.z = f2bf(v2); lv.z = f2bf(v2 - bf2f(hv.z));
        hv.w = f2bf(v3); lv.w = f2bf(v3 - bf2f(hv.w));
        *(ushort4*)(vth + obase) = hv;
        *(ushort4*)(vtl + obase) = lv;
      }
    }
  } else {
    #pragma unroll
    for (int j = 0; j < 4; ++j) {
      int col = n0 + wc + (j << 4) + l15;
      float bb = (MODE == 1) ? b0[col] : bias_sel0(b0, b1, col);
      #pragma unroll
      for (int i = 0; i < 4; ++i) {
        int rbase = m0 + wr + (i << 4) + (lg << 2);
        #pragma unroll
        for (int r = 0; r < 4; ++r)
          C[(size_t)(rbase + r) * N + col] = acc[i][j][r] + bb;
      }
    }
  }
}

// ---------------------------------------------------------------------------
// l2norm q,k -> split bf16 arrays qk_h/qk_l [8192][2048] (q | k), tier 1.
// ---------------------------------------------------------------------------
__global__ __launch_bounds__(256)
void qk_norm_split(const float* __restrict__ qkv, const float* __restrict__ scale_mul,
                   unsigned short* __restrict__ qk_h, unsigned short* __restrict__ qk_l)
{
  int wave = (blockIdx.x << 2) + (threadIdx.x >> 6);
  int lane = threadIdx.x & 63;
  int h  = wave & 15;
  int bl = wave >> 4;
  size_t base = (size_t)bl * 3072 + (h << 6) + lane;
  float q = qkv[base];
  float k = qkv[base + 1024];
  float sq = q * q, sk = k * k;
  #pragma unroll
  for (int off = 32; off; off >>= 1) {
    sq += __shfl_xor(sq, off);
    sk += __shfl_xor(sk, off);
  }
  float sm = __expf(fminf(scale_mul[h], LN100));
  q = q / fmaxf(sqrtf(sq), 1e-12f) * sm;
  k = k / fmaxf(sqrtf(sk), 1e-12f);
  size_t ob = (size_t)bl * 2048 + (h << 6) + lane;
  unsigned short qh = f2bf(q);
  qk_h[ob] = qh;          qk_l[ob] = f2bf(q - bf2f(qh));
  unsigned short kh = f2bf(k);
  qk_h[ob + 1024] = kh;   qk_l[ob + 1024] = f2bf(k - bf2f(kh));
}

// ---------------------------------------------------------------------------
// Split-bf16 MFMA flash attention, QBLK=128.
// Block = (b,h,qtile 128 rows), 4 waves; wave w owns q rows 32w..32w+31
// (two 16-row fragments qf=0,1). KVBLK=64 staged via global_load_lds.
// K/V LDS reads hoisted and shared across both q-fragments.
// Bias preloaded to regs between the staging barriers (hides under drain).
// All LDS tiles: rows x 128B, chunk swizzle c^=(row&7) -> <=2-way conflicts.
// ---------------------------------------------------------------------------
__global__ __launch_bounds__(256, 2)
void attn_mfma(const unsigned short* __restrict__ qk_h, const unsigned short* __restrict__ qk_l,
               const unsigned short* __restrict__ vth, const unsigned short* __restrict__ vtl,
               const float* __restrict__ bias,
               unsigned short* __restrict__ oh, unsigned short* __restrict__ ol)
{
  __shared__ unsigned short sKh[4096], sKl[4096];    // 64 kv rows x 64 u16
  __shared__ unsigned short sVh[4096], sVl[4096];    // 64 d rows x 64 u16
  __shared__ unsigned short sPh[8192], sPl[8192];    // 128 q rows x 64 u16

  const int tid  = threadIdx.x;
  const int lane = tid & 63;
  const int l15  = lane & 15, lg = lane >> 4;
  const int w    = tid >> 6;
  const int qt = blockIdx.x & 7;
  const int h  = (blockIdx.x >> 3) & 15;
  const int b  = blockIdx.x >> 7;
  const int q0 = qt << 7;

  // Q fragments (A-operand): qf strip rows q0+32w+16qf+l15, d-chunk lg*8 + ks*32
  short8 qh[2][2], qlo[2][2];
  #pragma unroll
  for (int qf = 0; qf < 2; ++qf) {
    size_t rb = ((size_t)((b << 10) + q0 + (w << 5) + (qf << 4) + l15)) * 2048
              + (h << 6) + (lg << 3);
    qh[qf][0]  = *(const short8*)(qk_h + rb);
    qh[qf][1]  = *(const short8*)(qk_h + rb + 32);
    qlo[qf][0] = *(const short8*)(qk_l + rb);
    qlo[qf][1] = *(const short8*)(qk_l + rb + 32);
  }

  f32x4 ao[2][4];
  float mr[2][4], lr[2][4];
  #pragma unroll
  for (int qf = 0; qf < 2; ++qf) {
    #pragma unroll
    for (int j = 0; j < 4; ++j) ao[qf][j] = (f32x4){0.f, 0.f, 0.f, 0.f};
    #pragma unroll
    for (int r = 0; r < 4; ++r) { mr[qf][r] = -3.0e38f; lr[qf][r] = 0.0f; }
  }

  const unsigned short* kh_base = qk_h + 1024 + (h << 6);
  const unsigned short* kl_base = qk_l + 1024 + (h << 6);
  const size_t vbase = ((size_t)((b << 4) + h)) * 65536;

  for (int kv0 = 0; kv0 < 1024; kv0 += 64) {
    __syncthreads();
    // ---- stage K (64x64) and V^T (64x64), hi/lo, swizzled ----
    #pragma unroll
    for (int u = 0; u < 2; ++u) {
      int idx = (u << 8) + tid;        // 0..511
      int r = idx >> 3, c = idx & 7;
      int s = c ^ (r & 7);
      size_t krow = (size_t)((b << 10) + kv0 + r) * 2048 + (s << 3);
      size_t vrow = vbase + (size_t)r * 1024 + kv0 + (s << 3);
      G2L16(kh_base + krow, sKh + (idx << 3));
      G2L16(kl_base + krow, sKl + (idx << 3));
      G2L16(vth + vrow,     sVh + (idx << 3));
      G2L16(vtl + vrow,     sVl + (idx << 3));
    }
    // ---- bias preload (overlaps the staging drain) ----
    float bb[2][4][4];
    #pragma unroll
    for (int qf = 0; qf < 2; ++qf)
      #pragma unroll
      for (int r = 0; r < 4; ++r) {
        int qrow = q0 + (w << 5) + (qf << 4) + (lg << 2) + r;
        const float* bp = bias + ((size_t)h << 20) + (size_t)qrow * 1024 + kv0 + l15;
        #pragma unroll
        for (int j = 0; j < 4; ++j) bb[qf][r][j] = bp[j << 4];
      }
    __syncthreads();

    // ---- S = Q.K^T : K fragments shared across both q-fragments ----
    f32x4 sv[2][4];
    #pragma unroll
    for (int j = 0; j < 4; ++j) {
      f32x4 a0 = (f32x4){0.f, 0.f, 0.f, 0.f};
      f32x4 a1 = (f32x4){0.f, 0.f, 0.f, 0.f};
      #pragma unroll
      for (int ks = 0; ks < 2; ++ks) {
        int row = (j << 4) + l15;
        int c   = (lg + (ks << 2)) ^ (row & 7);
        short8 kh = *(const short8*)(sKh + (row << 6) + (c << 3));
        short8 kl = *(const short8*)(sKl + (row << 6) + (c << 3));
        a0 = MFMA_BF16(qh[0][ks], kh, a0);
        a0 = MFMA_BF16(qh[0][ks], kl, a0);
        a0 = MFMA_BF16(qlo[0][ks], kh, a0);
        a1 = MFMA_BF16(qh[1][ks], kh, a1);
        a1 = MFMA_BF16(qh[1][ks], kl, a1);
        a1 = MFMA_BF16(qlo[1][ks], kh, a1);
      }
      sv[0][j] = a0;
      sv[1][j] = a1;
    }

    // ---- bias + online softmax + P write, per q-fragment ----
    #pragma unroll
    for (int qf = 0; qf < 2; ++qf) {
      float p[4][4], alpha[4];
      #pragma unroll
      for (int r = 0; r < 4; ++r) {
        float s0 = sv[qf][0][r] + bb[qf][r][0];
        float s1 = sv[qf][1][r] + bb[qf][r][1];
        float s2 = sv[qf][2][r] + bb[qf][r][2];
        float s3 = sv[qf][3][r] + bb[qf][r][3];
        float mx = fmaxf(fmaxf(s0, s1), fmaxf(s2, s3));
        #pragma unroll
        for (int o = 1; o < 16; o <<= 1) mx = fmaxf(mx, __shfl_xor(mx, o));
        float mn = fmaxf(mr[qf][r], mx);
        alpha[r] = __expf(mr[qf][r] - mn);
        p[r][0] = __expf(s0 - mn); p[r][1] = __expf(s1 - mn);
        p[r][2] = __expf(s2 - mn); p[r][3] = __expf(s3 - mn);
        float rs = p[r][0] + p[r][1] + p[r][2] + p[r][3];
        #pragma unroll
        for (int o = 1; o < 16; o <<= 1) rs += __shfl_xor(rs, o);
        lr[qf][r] = lr[qf][r] * alpha[r] + rs;
        mr[qf][r] = mn;
      }
      #pragma unroll
      for (int jd = 0; jd < 4; ++jd)
        #pragma unroll
        for (int r = 0; r < 4; ++r)
          ao[qf][jd][r] *= alpha[r];
      // write P (hi/lo) to own-wave LDS strip (no barrier needed)
      #pragma unroll
      for (int r = 0; r < 4; ++r) {
        int q2 = (w << 5) + (qf << 4) + (lg << 2) + r;
        #pragma unroll
        for (int j = 0; j < 4; ++j) {
          unsigned short hb = f2bf(p[r][j]);
          unsigned short lb = f2bf(p[r][j] - bf2f(hb));
          int c = ((j << 1) + (l15 >> 3)) ^ (q2 & 7);
          int e = (q2 << 6) + (c << 3) + (l15 & 7);
          sPh[e] = hb;
          sPl[e] = lb;
        }
      }
    }

    // ---- O += P.V : V fragments shared across both q-fragments ----
    #pragma unroll
    for (int ks = 0; ks < 2; ++ks) {
      short8 ph[2], pl[2];
      #pragma unroll
      for (int qf = 0; qf < 2; ++qf) {
        int prow = (w << 5) + (qf << 4) + l15;
        int pc   = (lg + (ks << 2)) ^ (prow & 7);
        ph[qf] = *(const short8*)(sPh + (prow << 6) + (pc << 3));
        pl[qf] = *(const short8*)(sPl + (prow << 6) + (pc << 3));
      }
      #pragma unroll
      for (int jd = 0; jd < 4; ++jd) {
        int vrow = (jd << 4) + l15;
        int vc   = (lg + (ks << 2)) ^ (vrow & 7);
        short8 vh = *(const short8*)(sVh + (vrow << 6) + (vc << 3));
        short8 vl = *(const short8*)(sVl + (vrow << 6) + (vc << 3));
        #pragma unroll
        for (int qf = 0; qf < 2; ++qf) {
          ao[qf][jd] = MFMA_BF16(ph[qf], vh, ao[qf][jd]);
          ao[qf][jd] = MFMA_BF16(ph[qf], vl, ao[qf][jd]);
          ao[qf][jd] = MFMA_BF16(pl[qf], vh, ao[qf][jd]);
        }
      }
    }
  }

  // epilogue: O /= l ; write split bf16 att [B,L,C]
  #pragma unroll
  for (int qf = 0; qf < 2; ++qf)
    #pragma unroll
    for (int r = 0; r < 4; ++r) {
      float inv = 1.0f / lr[qf][r];
      size_t orow = ((size_t)((b << 10) + q0 + (w << 5) + (qf << 4) + (lg << 2) + r)) * 1024
                  + (h << 6) + l15;
      #pragma unroll
      for (int jd = 0; jd < 4; ++jd) {
        float v = ao[qf][jd][r] * inv;
        unsigned short hb = f2bf(v);
        oh[orow + (jd << 4)] = hb;
        ol[orow + (jd << 4)] = f2bf(v - bf2f(hb));
      }
    }
}

// ---------------------------------------------------------------------------
// fp32 fallback GEMM
// ---------------------------------------------------------------------------
template <int MODE>
__global__ __launch_bounds__(256)
void gemm_nt(const float* __restrict__ A, const float* __restrict__ Bw,
             const float* __restrict__ b0, const float* __restrict__ b1,
             float* __restrict__ C, int M, int N, int K)
{
  __shared__ float As[32][132];
  __shared__ float Bs[32][132];
  const int tid = threadIdx.x;
  const int tx = tid & 15, ty = tid >> 4;
  const int m0 = blockIdx.y << 7;
  const int n0 = blockIdx.x << 7;

  float acc[8][8];
  #pragma unroll
  for (int i = 0; i < 8; ++i)
    #pragma unroll
    for (int j = 0; j < 8; ++j) acc[i][j] = 0.0f;

  for (int k0 = 0; k0 < K; k0 += 32) {
    #pragma unroll
    for (int u = 0; u < 4; ++u) {
      int f   = tid + (u << 8);
      int row = f >> 3;
      int kk  = (f & 7) << 2;
      float4 av = *(const float4*)(A  + (size_t)(m0 + row) * K + k0 + kk);
      As[kk + 0][row] = av.x; As[kk + 1][row] = av.y;
      As[kk + 2][row] = av.z; As[kk + 3][row] = av.w;
      float4 bv = *(const float4*)(Bw + (size_t)(n0 + row) * K + k0 + kk);
      Bs[kk + 0][row] = bv.x; Bs[kk + 1][row] = bv.y;
      Bs[kk + 2][row] = bv.z; Bs[kk + 3][row] = bv.w;
    }
    __syncthreads();
    #pragma unroll
    for (int kk = 0; kk < 32; ++kk) {
      float a[8], b[8];
      *(float4*)(a)     = *(const float4*)(&As[kk][(ty << 3)]);
      *(float4*)(a + 4) = *(const float4*)(&As[kk][(ty << 3) + 4]);
      *(float4*)(b)     = *(const float4*)(&Bs[kk][(tx << 3)]);
      *(float4*)(b + 4) = *(const float4*)(&Bs[kk][(tx << 3) + 4]);
      #pragma unroll
      for (int i = 0; i < 8; ++i)
        #pragma unroll
        for (int j = 0; j < 8; ++j)
          acc[i][j] = fmaf(a[i], b[j], acc[i][j]);
    }
    __syncthreads();
  }

  #pragma unroll
  for (int i = 0; i < 8; ++i) {
    int row = m0 + (ty << 3) + i;
    #pragma unroll
    for (int j4 = 0; j4 < 2; ++j4) {
      int col = n0 + (tx << 3) + (j4 << 2);
      float4 r;
      float bb[4];
      #pragma unroll
      for (int j = 0; j < 4; ++j)
        bb[j] = (MODE == 0) ? bias_sel0(b0, b1, col + j) : b0[col + j];
      r.x = acc[i][j4 * 4 + 0] + bb[0];
      r.y = acc[i][j4 * 4 + 1] + bb[1];
      r.z = acc[i][j4 * 4 + 2] + bb[2];
      r.w = acc[i][j4 * 4 + 3] + bb[3];
      *(float4*)(C + (size_t)row * N + col) = r;
    }
  }
}

// ---------------------------------------------------------------------------
// fp32 in-place qk norm (tiers 2/3)
// ---------------------------------------------------------------------------
__global__ __launch_bounds__(256)
void qk_norm(float* __restrict__ qkv, const float* __restrict__ scale_mul)
{
  int wave = (blockIdx.x << 2) + (threadIdx.x >> 6);
  int lane = threadIdx.x & 63;
  int h  = wave & 15;
  int bl = wave >> 4;
  size_t base = (size_t)bl * 3072 + (h << 6) + lane;
  float q = qkv[base];
  float k = qkv[base + 1024];
  float sq = q * q, sk = k * k;
  #pragma unroll
  for (int off = 32; off; off >>= 1) {
    sq += __shfl_xor(sq, off);
    sk += __shfl_xor(sk, off);
  }
  float sm = __expf(fminf(scale_mul[h], LN100));
  q = q / fmaxf(sqrtf(sq), 1e-12f) * sm;
  k = k / fmaxf(sqrtf(sk), 1e-12f);
  qkv[base]        = q;
  qkv[base + 1024] = k;
}

// ---------------------------------------------------------------------------
// fp32 flash attention (tiers 2/3). OUTMODE 0: fp32 out; 1: split bf16 out.
// ---------------------------------------------------------------------------
#define SW(r, c4) ((((c4) ^ ((r) >> 2)) & 15) << 2)

template <int OUTMODE>
__global__ __launch_bounds__(256)
void attn_fwd(const float* __restrict__ qkv, const float* __restrict__ bias,
              float* __restrict__ aout,
              unsigned short* __restrict__ ah, unsigned short* __restrict__ al)
{
  __shared__ float Qs[64][64];
  __shared__ float Ks[64][64];
  __shared__ float Vs[64][64];
  __shared__ float Ps[64][64];

  const int tid = threadIdx.x;
  const int tx = tid & 15, ty = tid >> 4;
  const int qt = blockIdx.x & 15;
  const int h  = (blockIdx.x >> 4) & 15;
  const int b  = blockIdx.x >> 8;
  const int q0 = qt << 6;

  #pragma unroll
  for (int u = 0; u < 4; ++u) {
    int f = tid + (u << 8);
    int r = f >> 4, c4 = f & 15;
    float4 v = *(const float4*)(qkv + (size_t)(b * 1024 + q0 + r) * 3072 + (h << 6) + (c4 << 2));
    *(float4*)(&Qs[r][SW(r, c4)]) = v;
  }

  float o[4][4];
  float mr[4], lr[4];
  #pragma unroll
  for (int i = 0; i < 4; ++i) {
    mr[i] = -3.0e38f; lr[i] = 0.0f;
    #pragma unroll
    for (int j = 0; j < 4; ++j) o[i][j] = 0.0f;
  }

  for (int kv0 = 0; kv0 < 1024; kv0 += 64) {
    __syncthreads();
    #pragma unroll
    for (int u = 0; u < 4; ++u) {
      int f = tid + (u << 8);
      int r = f >> 4, c4 = f & 15;
      size_t gb = (size_t)(b * 1024 + kv0 + r) * 3072 + (h << 6) + (c4 << 2);
      *(float4*)(&Ks[r][SW(r, c4)]) = *(const float4*)(qkv + gb + 1024);
      *(float4*)(&Vs[r][SW(r, c4)]) = *(const float4*)(qkv + gb + 2048);
    }
    __syncthreads();

    float s[4][4];
    #pragma unroll
    for (int i = 0; i < 4; ++i)
      #pragma unroll
      for (int j = 0; j < 4; ++j) s[i][j] = 0.0f;

    #pragma unroll 4
    for (int d4 = 0; d4 < 16; ++d4) {
      float4 qv[4], kv[4];
      #pragma unroll
      for (int i = 0; i < 4; ++i)
        qv[i] = *(const float4*)(&Qs[(ty << 2) + i][SW((ty << 2) + i, d4)]);
      #pragma unroll
      for (int j = 0; j < 4; ++j)
        kv[j] = *(const float4*)(&Ks[(tx << 2) + j][SW((tx << 2) + j, d4)]);
      #pragma unroll
      for (int i = 0; i < 4; ++i)
        #pragma unroll
        for (int j = 0; j < 4; ++j)
          s[i][j] += qv[i].x * kv[j].x + qv[i].y * kv[j].y +
                     qv[i].z * kv[j].z + qv[i].w * kv[j].w;
    }

    float p[4][4];
    #pragma unroll
    for (int i = 0; i < 4; ++i) {
      float4 bv = *(const float4*)(bias + (size_t)((h << 10) + q0 + (ty << 2) + i) * 1024
                                        + kv0 + (tx << 2));
      s[i][0] += bv.x; s[i][1] += bv.y; s[i][2] += bv.z; s[i][3] += bv.w;
      float mx = fmaxf(fmaxf(s[i][0], s[i][1]), fmaxf(s[i][2], s[i][3]));
      #pragma unroll
      for (int off = 1; off < 16; off <<= 1) mx = fmaxf(mx, __shfl_xor(mx, off));
      float mn = fmaxf(mr[i], mx);
      float alp = __expf(mr[i] - mn);
      float rs = 0.0f;
      #pragma unroll
      for (int j = 0; j < 4; ++j) { p[i][j] = __expf(s[i][j] - mn); rs += p[i][j]; }
      #pragma unroll
      for (int off = 1; off < 16; off <<= 1) rs += __shfl_xor(rs, off);
      lr[i] = lr[i] * alp + rs;
      mr[i] = mn;
      #pragma unroll
      for (int j = 0; j < 4; ++j) o[i][j] *= alp;
    }

    #pragma unroll
    for (int jj = 0; jj < 4; ++jj)
      #pragma unroll
      for (int i = 0; i < 4; ++i)
        Ps[(tx << 2) + jj][SW((tx << 2) + jj, ty) + i] = p[i][jj];
    __syncthreads();

    #pragma unroll 8
    for (int j = 0; j < 64; ++j) {
      float4 pv = *(const float4*)(&Ps[j][SW(j, ty)]);
      float4 vv = *(const float4*)(&Vs[j][SW(j, tx)]);
      o[0][0] += pv.x * vv.x; o[0][1] += pv.x * vv.y; o[0][2] += pv.x * vv.z; o[0][3] += pv.x * vv.w;
      o[1][0] += pv.y * vv.x; o[1][1] += pv.y * vv.y; o[1][2] += pv.y * vv.z; o[1][3] += pv.y * vv.w;
      o[2][0] += pv.z * vv.x; o[2][1] += pv.z * vv.y; o[2][2] += pv.z * vv.z; o[2][3] += pv.z * vv.w;
      o[3][0] += pv.w * vv.x; o[3][1] += pv.w * vv.y; o[3][2] += pv.w * vv.z; o[3][3] += pv.w * vv.w;
    }
  }

  #pragma unroll
  for (int i = 0; i < 4; ++i) {
    float inv = 1.0f / lr[i];
    float v0 = o[i][0] * inv, v1 = o[i][1] * inv, v2 = o[i][2] * inv, v3 = o[i][3] * inv;
    if (OUTMODE == 0) {
      float4 r; r.x = v0; r.y = v1; r.z = v2; r.w = v3;
      *(float4*)(aout + (size_t)(b * 1024 + q0 + (ty << 2) + i) * 1024 + (h << 6) + (tx << 2)) = r;
    } else {
      ushort4 hh, ll;
      hh.x = f2bf(v0); ll.x = f2bf(v0 - bf2f(hh.x));
      hh.y = f2bf(v1); ll.y = f2bf(v1 - bf2f(hh.y));
      hh.z = f2bf(v2); ll.z = f2bf(v2 - bf2f(hh.z));
      hh.w = f2bf(v3); ll.w = f2bf(v3 - bf2f(hh.w));
      size_t idx = (size_t)(b * 1024 + q0 + (ty << 2) + i) * 256 + (h << 4) + tx;
      ((ushort4*)ah)[idx] = hh;
      ((ushort4*)al)[idx] = ll;
    }
  }
}

// ---------------------------------------------------------------------------
extern "C" void kernel_launch(void* const* d_in, const int* in_sizes, int n_in,
                              void* d_out, int out_size, void* d_ws, size_t ws_size,
                              hipStream_t stream) {
  const float* x         = (const float*)d_in[0];
  const float* attn_bias = (const float*)d_in[1];
  const float* w_qkv     = (const float*)d_in[2];
  const float* q_bias    = (const float*)d_in[3];
  const float* v_bias    = (const float*)d_in[4];
  const float* scale_mul = (const float*)d_in[5];
  const float* w_proj    = (const float*)d_in[6];
  const float* b_proj    = (const float*)d_in[7];
  float* out = (float*)d_out;

  const size_t MiB = 1024 * 1024;
  char* ws = (char*)d_ws;
  dim3 blk(256);

  if (ws_size >= 240 * MiB) {
    // ---- tier 1: full MFMA path ----
    float*          qkv = (float*)ws;                         // q/k thirds only
    unsigned short* xh  = (unsigned short*)(ws + 96  * MiB);  // -> att_h
    unsigned short* xl  = (unsigned short*)(ws + 112 * MiB);  // -> att_l
    unsigned short* qkh = (unsigned short*)(ws + 128 * MiB);
    unsigned short* qkl = (unsigned short*)(ws + 160 * MiB);
    unsigned short* vth = (unsigned short*)(ws + 192 * MiB);
    unsigned short* vtl = (unsigned short*)(ws + 208 * MiB);
    unsigned short* wqh = (unsigned short*)(ws + 224 * MiB);
    unsigned short* wql = (unsigned short*)(ws + 230 * MiB);
    unsigned short* wph = (unsigned short*)(ws + 236 * MiB);
    unsigned short* wpl = (unsigned short*)(ws + 238 * MiB);

    split_f32_bf16<<<dim3(8192), blk, 0, stream>>>(x,      xh,  xl,  2097152);
    split_f32_bf16<<<dim3(3072), blk, 0, stream>>>(w_qkv,  wqh, wql, 786432);
    split_f32_bf16<<<dim3(1024), blk, 0, stream>>>(w_proj, wph, wpl, 262144);

    // qkv GEMM: q/k -> fp32 qkv; V -> vth/vtl directly (transposed split bf16)
    gemm_nt_split<0><<<dim3(24, 64), blk, 0, stream>>>(xh, xl, wqh, wql,
        q_bias, v_bias, qkv, vth, vtl, 8192, 3072, 1024);
    qk_norm_split<<<dim3(32768), blk, 0, stream>>>(qkv, scale_mul, qkh, qkl);
    attn_mfma<<<dim3(1024), blk, 0, stream>>>(qkh, qkl, vth, vtl, attn_bias, xh, xl);
    gemm_nt_split<1><<<dim3(8, 64), blk, 0, stream>>>(xh, xl, wph, wpl,
        b_proj, nullptr, out, nullptr, nullptr, 8192, 1024, 1024);
  } else if (ws_size >= 144 * MiB) {
    // ---- tier 2: MFMA GEMMs + fp32 attention ----
    float*          qkv = (float*)ws;
    unsigned short* xh  = (unsigned short*)(ws + 96  * MiB);
    unsigned short* xl  = (unsigned short*)(ws + 112 * MiB);
    unsigned short* wqh = (unsigned short*)(ws + 128 * MiB);
    unsigned short* wql = (unsigned short*)(ws + 134 * MiB);
    unsigned short* wph = (unsigned short*)(ws + 140 * MiB);
    unsigned short* wpl = (unsigned short*)(ws + 142 * MiB);

    split_f32_bf16<<<dim3(8192), blk, 0, stream>>>(x,      xh,  xl,  2097152);
    split_f32_bf16<<<dim3(3072), blk, 0, stream>>>(w_qkv,  wqh, wql, 786432);
    split_f32_bf16<<<dim3(1024), blk, 0, stream>>>(w_proj, wph, wpl, 262144);

    gemm_nt_split<2><<<dim3(24, 64), blk, 0, stream>>>(xh, xl, wqh, wql,
        q_bias, v_bias, qkv, nullptr, nullptr, 8192, 3072, 1024);
    qk_norm<<<dim3(32768), blk, 0, stream>>>(qkv, scale_mul);
    attn_fwd<1><<<dim3(2048), blk, 0, stream>>>(qkv, attn_bias, nullptr, xh, xl);
    gemm_nt_split<1><<<dim3(8, 64), blk, 0, stream>>>(xh, xl, wph, wpl,
        b_proj, nullptr, out, nullptr, nullptr, 8192, 1024, 1024);
  } else {
    // ---- tier 3: pure fp32 ----
    float* qkv = (float*)ws;
    float* att = qkv + (size_t)8192 * 3072;
    gemm_nt<0><<<dim3(24, 64), blk, 0, stream>>>(x, w_qkv, q_bias, v_bias, qkv, 8192, 3072, 1024);
    qk_norm<<<dim3(32768), blk, 0, stream>>>(qkv, scale_mul);
    attn_fwd<0><<<dim3(2048), blk, 0, stream>>>(qkv, attn_bias, att, nullptr, nullptr);
    gemm_nt<1><<<dim3(8, 64), blk, 0, stream>>>(att, w_proj, b_proj, nullptr, out, 8192, 1024, 1024);
  }
}

// Round 6
// 540.933 us; speedup vs baseline: 1.1996x; 1.1134x over previous
//
#include <hip/hip_runtime.h>
#include <hip/hip_bf16.h>

// ---------------------------------------------------------------------------
// SelfAttention fused pipeline — round 6.
//   B=8, L=1024, C=1024, H=16, D=64
// Tier 1 (ws >= 240 MiB): split-bf16 MFMA GEMMs + swapped-operand MFMA flash
//   attention (S^T = mfma(K,Q) so P stays in registers; no P LDS round-trip).
// Tier 2 (ws >= 144 MiB): split-bf16 MFMA GEMMs + fp32 flash attn.
// Tier 3 (else, needs 128 MiB): pure fp32 path.
// ---------------------------------------------------------------------------

#define LN100 4.6051701859880914f

typedef __attribute__((ext_vector_type(8))) short short8;
typedef __attribute__((ext_vector_type(4))) short short4v;
typedef __attribute__((ext_vector_type(4))) float f32x4;

#define MFMA_BF16(a, b, c) __builtin_amdgcn_mfma_f32_16x16x32_bf16(a, b, c, 0, 0, 0)

__device__ __forceinline__ unsigned short f2bf(float f) {
  unsigned u = __float_as_uint(f);
  u += 0x7fffu + ((u >> 16) & 1u);          // RNE (no NaNs in this workload)
  return (unsigned short)(u >> 16);
}
__device__ __forceinline__ float bf2f(unsigned short h) {
  return __uint_as_float(((unsigned)h) << 16);
}
// pack two f32 -> u32 of {bf16(a) lo, bf16(b) hi}, RNE (v_cvt_pk path)
__device__ __forceinline__ unsigned int pkbf2(float a, float b) {
  union { __hip_bfloat162 t; unsigned int u; } c;
  c.t = __float22bfloat162_rn(make_float2(a, b));
  return c.u;
}

__device__ __forceinline__ float bias_sel0(const float* qb, const float* vb, int col) {
  if (col < 1024) return qb[col];
  if (col < 2048) return 0.0f;
  return vb[col - 2048];
}

#define G2L16(gp, lp) __builtin_amdgcn_global_load_lds( \
    (const __attribute__((address_space(1))) void*)(gp), \
    (__attribute__((address_space(3))) void*)(lp), 16, 0, 0)

// ---------------------------------------------------------------------------
// split fp32 -> (hi, lo) bf16 pair, 4 elems/thread
// ---------------------------------------------------------------------------
__global__ __launch_bounds__(256)
void split_f32_bf16(const float* __restrict__ in, unsigned short* __restrict__ hi,
                    unsigned short* __restrict__ lo, int n4)
{
  int i = blockIdx.x * blockDim.x + threadIdx.x;
  if (i >= n4) return;
  float4 v = ((const float4*)in)[i];
  ushort4 h, l;
  h.x = f2bf(v.x); l.x = f2bf(v.x - bf2f(h.x));
  h.y = f2bf(v.y); l.y = f2bf(v.y - bf2f(h.y));
  h.z = f2bf(v.z); l.z = f2bf(v.z - bf2f(h.z));
  h.w = f2bf(v.w); l.w = f2bf(v.w - bf2f(h.w));
  ((ushort4*)hi)[i] = h;
  ((ushort4*)lo)[i] = l;
}

// ---------------------------------------------------------------------------
// Split-bf16 MFMA GEMM (unchanged from round 5, verified).
// MODE 0: qkv GEMM, tier-1 — q/k cols -> fp32 C; V cols -> vth/vtl direct.
// MODE 1: proj GEMM. MODE 2: qkv GEMM plain fp32 (tier 2).
// ---------------------------------------------------------------------------
template <int MODE>
__global__ __launch_bounds__(256)
void gemm_nt_split(const unsigned short* __restrict__ Ah, const unsigned short* __restrict__ Al,
                   const unsigned short* __restrict__ Wh, const unsigned short* __restrict__ Wl,
                   const float* __restrict__ b0, const float* __restrict__ b1,
                   float* __restrict__ C,
                   unsigned short* __restrict__ vth, unsigned short* __restrict__ vtl,
                   int M, int N, int K)
{
  __shared__ unsigned short sA[128 * 64];
  __shared__ unsigned short sW[128 * 64];

  const int tid  = threadIdx.x;
  const int lane = tid & 63;
  const int l15  = lane & 15, lg = lane >> 4;
  const int w    = tid >> 6;
  const int wr   = (w >> 1) << 6;
  const int wc   = (w & 1) << 6;
  const int m0   = blockIdx.y << 7;
  const int n0   = blockIdx.x << 7;

  f32x4 acc[4][4];
  #pragma unroll
  for (int i = 0; i < 4; ++i)
    #pragma unroll
    for (int j = 0; j < 4; ++j)
      acc[i][j] = (f32x4){0.f, 0.f, 0.f, 0.f};

  for (int k0 = 0; k0 < K; k0 += 32) {
    __syncthreads();
    #pragma unroll
    for (int u = 0; u < 4; ++u) {
      int idx = (u << 8) + tid;
      int row = idx >> 3;
      int c   = idx & 7;
      int s   = c ^ (row & 7);
      size_t rbA = (size_t)(m0 + row) * K + k0;
      size_t rbW = (size_t)(n0 + row) * K + k0;
      const unsigned short* srcA = (s < 4) ? (Ah + rbA + (s << 3))
                                           : (Al + rbA + ((s - 4) << 3));
      const unsigned short* srcW = (s < 4) ? (Wh + rbW + (s << 3))
                                           : (Wl + rbW + ((s - 4) << 3));
      G2L16(srcA, sA + (idx << 3));
      G2L16(srcW, sW + (idx << 3));
    }
    __syncthreads();

    short8 ah[4], al[4];
    #pragma unroll
    for (int i = 0; i < 4; ++i) {
      int row = wr + (i << 4) + l15;
      ah[i] = *(const short8*)(sA + (row << 6) + ((lg       ^ (row & 7)) << 3));
      al[i] = *(const short8*)(sA + (row << 6) + (((4 + lg) ^ (row & 7)) << 3));
    }
    #pragma unroll
    for (int j = 0; j < 4; ++j) {
      int row = wc + (j << 4) + l15;
      short8 wh = *(const short8*)(sW + (row << 6) + ((lg       ^ (row & 7)) << 3));
      short8 wl = *(const short8*)(sW + (row << 6) + (((4 + lg) ^ (row & 7)) << 3));
      #pragma unroll
      for (int i = 0; i < 4; ++i) {
        acc[i][j] = MFMA_BF16(ah[i], wh, acc[i][j]);
        acc[i][j] = MFMA_BF16(ah[i], wl, acc[i][j]);
        acc[i][j] = MFMA_BF16(al[i], wh, acc[i][j]);
      }
    }
  }

  if (MODE == 0 && n0 >= 2048) {
    #pragma unroll
    for (int j = 0; j < 4; ++j) {
      int col = n0 + wc + (j << 4) + l15;
      int d   = col - 2048;
      int hh  = d >> 6, dd = d & 63;
      float bb = b1[d];
      #pragma unroll
      for (int i = 0; i < 4; ++i) {
        int row  = m0 + wr + (i << 4) + (lg << 2);
        int bidx = row >> 10;
        int l    = row & 1023;
        size_t obase = ((((size_t)bidx << 4) + hh) << 6) + dd;
        obase = obase * 1024 + l;
        ushort4 hv, lv;
        float v0 = acc[i][j][0] + bb;
        float v1 = acc[i][j][1] + bb;
        float v2 = acc[i][j][2] + bb;
        float v3 = acc[i][j][3] + bb;
        hv.x = f2bf(v0); lv.x = f2bf(v0 - bf2f(hv.x));
        hv.y = f2bf(v1); lv.y = f2bf(v1 - bf2f(hv.y));
        hv.z = f2bf(v2); lv.z = f2bf(v2 - bf2f(hv.z));
        hv.w = f2bf(v3); lv.w = f2bf(v3 - bf2f(hv.w));
        *(ushort4*)(vth + obase) = hv;
        *(ushort4*)(vtl + obase) = lv;
      }
    }
  } else {
    #pragma unroll
    for (int j = 0; j < 4; ++j) {
      int col = n0 + wc + (j << 4) + l15;
      float bb = (MODE == 1) ? b0[col] : bias_sel0(b0, b1, col);
      #pragma unroll
      for (int i = 0; i < 4; ++i) {
        int rbase = m0 + wr + (i << 4) + (lg << 2);
        #pragma unroll
        for (int r = 0; r < 4; ++r)
          C[(size_t)(rbase + r) * N + col] = acc[i][j][r] + bb;
      }
    }
  }
}

// ---------------------------------------------------------------------------
// l2norm q,k -> split bf16 arrays qk_h/qk_l [8192][2048] (q | k), tier 1.
// ---------------------------------------------------------------------------
__global__ __launch_bounds__(256)
void qk_norm_split(const float* __restrict__ qkv, const float* __restrict__ scale_mul,
                   unsigned short* __restrict__ qk_h, unsigned short* __restrict__ qk_l)
{
  int wave = (blockIdx.x << 2) + (threadIdx.x >> 6);
  int lane = threadIdx.x & 63;
  int h  = wave & 15;
  int bl = wave >> 4;
  size_t base = (size_t)bl * 3072 + (h << 6) + lane;
  float q = qkv[base];
  float k = qkv[base + 1024];
  float sq = q * q, sk = k * k;
  #pragma unroll
  for (int off = 32; off; off >>= 1) {
    sq += __shfl_xor(sq, off);
    sk += __shfl_xor(sk, off);
  }
  float sm = __expf(fminf(scale_mul[h], LN100));
  q = q / fmaxf(sqrtf(sq), 1e-12f) * sm;
  k = k / fmaxf(sqrtf(sk), 1e-12f);
  size_t ob = (size_t)bl * 2048 + (h << 6) + lane;
  unsigned short qh = f2bf(q);
  qk_h[ob] = qh;          qk_l[ob] = f2bf(q - bf2f(qh));
  unsigned short kh = f2bf(k);
  qk_h[ob + 1024] = kh;   qk_l[ob + 1024] = f2bf(k - bf2f(kh));
}

// ---------------------------------------------------------------------------
// Swapped-operand split-bf16 MFMA flash attention, QBLK=128, KVBLK=64.
// Block = (b,h,128 q-rows), 4 waves; wave w owns q rows 32w..32w+31 as two
// 16-row fragments qf. S^T = mfma(A=K, B=Q): C/D col(l15)=q, row(lg*4+r+16j)=kv
// -> each lane holds a 64-wide P-row slice in registers.
// Softmax: lane-local over 16 regs + 2 shuffles (xor16/32).
// PV: A = P packed in-register (slot (lg,s) <-> kv = lg*4+(s&3)+16(s>>2)+32ks);
// B = V^T read as 2x ds_read_b64 matching the same slot map. No P LDS.
// Bias: float4 loads (4 consecutive kv per lane). LDS = 32 KiB (K,V hi/lo).
// ---------------------------------------------------------------------------
__global__ __launch_bounds__(256, 2)
void attn_mfma(const unsigned short* __restrict__ qk_h, const unsigned short* __restrict__ qk_l,
               const unsigned short* __restrict__ vth, const unsigned short* __restrict__ vtl,
               const float* __restrict__ bias,
               unsigned short* __restrict__ oh, unsigned short* __restrict__ ol)
{
  __shared__ unsigned short sKh[4096], sKl[4096];    // 64 kv rows x 64 u16
  __shared__ unsigned short sVh[4096], sVl[4096];    // 64 d rows x 64 u16

  const int tid  = threadIdx.x;
  const int lane = tid & 63;
  const int l15  = lane & 15, lg = lane >> 4;
  const int w    = tid >> 6;
  const int qt = blockIdx.x & 7;
  const int h  = (blockIdx.x >> 3) & 15;
  const int b  = blockIdx.x >> 7;
  const int q0 = qt << 7;

  // Q fragments (B-operand): lane l15 = q-row, chunk lg*8 + ks*32 over d
  short8 qh[2][2], qlo[2][2];
  #pragma unroll
  for (int qf = 0; qf < 2; ++qf) {
    size_t rb = ((size_t)((b << 10) + q0 + (w << 5) + (qf << 4) + l15)) * 2048
              + (h << 6) + (lg << 3);
    qh[qf][0]  = *(const short8*)(qk_h + rb);
    qh[qf][1]  = *(const short8*)(qk_h + rb + 32);
    qlo[qf][0] = *(const short8*)(qk_l + rb);
    qlo[qf][1] = *(const short8*)(qk_l + rb + 32);
  }

  f32x4 ao[2][4];            // [qf][jd] O: row q=lg*4+r, col d=jd*16+l15
  float mr[2], lr[2];        // per qf, this lane's q-row = l15
  #pragma unroll
  for (int qf = 0; qf < 2; ++qf) {
    #pragma unroll
    for (int j = 0; j < 4; ++j) ao[qf][j] = (f32x4){0.f, 0.f, 0.f, 0.f};
    mr[qf] = -3.0e38f; lr[qf] = 0.0f;
  }

  const unsigned short* kh_base = qk_h + 1024 + (h << 6);
  const unsigned short* kl_base = qk_l + 1024 + (h << 6);
  const size_t vbase = ((size_t)((b << 4) + h)) * 65536;
  const float* bias_base = bias + ((size_t)h << 20)
                         + (size_t)(q0 + (w << 5) + l15) * 1024 + (lg << 2);

  for (int kv0 = 0; kv0 < 1024; kv0 += 64) {
    __syncthreads();
    // ---- stage K (64x64) and V^T (64x64), hi/lo, swizzled ----
    #pragma unroll
    for (int u = 0; u < 2; ++u) {
      int idx = (u << 8) + tid;        // 0..511
      int r = idx >> 3, c = idx & 7;
      int s = c ^ (r & 7);
      size_t krow = (size_t)((b << 10) + kv0 + r) * 2048 + (s << 3);
      size_t vrow = vbase + (size_t)r * 1024 + kv0 + (s << 3);
      G2L16(kh_base + krow, sKh + (idx << 3));
      G2L16(kl_base + krow, sKl + (idx << 3));
      G2L16(vth + vrow,     sVh + (idx << 3));
      G2L16(vtl + vrow,     sVl + (idx << 3));
    }
    // ---- bias preload: float4 = 4 consecutive kv for this lane's q-row ----
    float4 bb[2][4];
    #pragma unroll
    for (int qf = 0; qf < 2; ++qf)
      #pragma unroll
      for (int j = 0; j < 4; ++j)
        bb[qf][j] = *(const float4*)(bias_base + (size_t)(qf << 4) * 1024
                                     + kv0 + (j << 4));
    __syncthreads();

    // ---- S^T = K.Q : sv[qf][j][r] = S[q=l15][kv=lg*4+r+16j] ----
    f32x4 sv[2][4];
    #pragma unroll
    for (int j = 0; j < 4; ++j) {
      int row = (j << 4) + l15;                 // kv row in tile
      int c0 = lg ^ (row & 7);
      int c1 = (lg + 4) ^ (row & 7);
      short8 kh0 = *(const short8*)(sKh + (row << 6) + (c0 << 3));
      short8 kl0 = *(const short8*)(sKl + (row << 6) + (c0 << 3));
      short8 kh1 = *(const short8*)(sKh + (row << 6) + (c1 << 3));
      short8 kl1 = *(const short8*)(sKl + (row << 6) + (c1 << 3));
      #pragma unroll
      for (int qf = 0; qf < 2; ++qf) {
        f32x4 a = (f32x4){0.f, 0.f, 0.f, 0.f};
        a = MFMA_BF16(kh0, qh[qf][0], a);
        a = MFMA_BF16(kl0, qh[qf][0], a);
        a = MFMA_BF16(kh0, qlo[qf][0], a);
        a = MFMA_BF16(kh1, qh[qf][1], a);
        a = MFMA_BF16(kl1, qh[qf][1], a);
        a = MFMA_BF16(kh1, qlo[qf][1], a);
        sv[qf][j] = a;
      }
    }

    // ---- softmax (lane-local) + in-register P pack ----
    unsigned int phw[2][8], plw[2][8];
    #pragma unroll
    for (int qf = 0; qf < 2; ++qf) {
      #pragma unroll
      for (int j = 0; j < 4; ++j) {
        sv[qf][j][0] += bb[qf][j].x;
        sv[qf][j][1] += bb[qf][j].y;
        sv[qf][j][2] += bb[qf][j].z;
        sv[qf][j][3] += bb[qf][j].w;
      }
      float mx = -3.0e38f;
      #pragma unroll
      for (int j = 0; j < 4; ++j)
        #pragma unroll
        for (int r = 0; r < 4; ++r) mx = fmaxf(mx, sv[qf][j][r]);
      mx = fmaxf(mx, __shfl_xor(mx, 16));
      mx = fmaxf(mx, __shfl_xor(mx, 32));
      float mn = fmaxf(mr[qf], mx);
      float al = __expf(mr[qf] - mn);
      mr[qf] = mn;
      float rs = 0.0f;
      #pragma unroll
      for (int j = 0; j < 4; ++j)
        #pragma unroll
        for (int r = 0; r < 4; ++r) {
          float e = __expf(sv[qf][j][r] - mn);
          sv[qf][j][r] = e;
          rs += e;
        }
      rs += __shfl_xor(rs, 16);
      rs += __shfl_xor(rs, 32);
      lr[qf] = lr[qf] * al + rs;
      // broadcast alpha from lane (q) to O-layout lanes (q = lg*4+r)
      #pragma unroll
      for (int r = 0; r < 4; ++r) {
        float av = __shfl(al, (lg << 2) + r);
        #pragma unroll
        for (int jd = 0; jd < 4; ++jd) ao[qf][jd][r] *= av;
      }
      // pack P hi/lo: word 2j   = {p[j][0], p[j][1]},
      //               word 2j+1 = {p[j][2], p[j][3]}
      #pragma unroll
      for (int j = 0; j < 4; ++j) {
        unsigned int h0 = pkbf2(sv[qf][j][0], sv[qf][j][1]);
        unsigned int h1 = pkbf2(sv[qf][j][2], sv[qf][j][3]);
        float r0 = sv[qf][j][0] - __uint_as_float(h0 << 16);
        float r1 = sv[qf][j][1] - __uint_as_float(h0 & 0xffff0000u);
        float r2 = sv[qf][j][2] - __uint_as_float(h1 << 16);
        float r3 = sv[qf][j][3] - __uint_as_float(h1 & 0xffff0000u);
        phw[qf][(j << 1)]     = h0;
        phw[qf][(j << 1) + 1] = h1;
        plw[qf][(j << 1)]     = pkbf2(r0, r1);
        plw[qf][(j << 1) + 1] = pkbf2(r2, r3);
      }
    }

    // ---- O += P.V : A = packed P (slot (lg,s) <-> kv=lg*4+(s&3)+16(s>>2)+32ks)
    //                 B = V^T via 2x ds_read_b64 matching the same slot map ----
    #pragma unroll
    for (int ks = 0; ks < 2; ++ks) {
      union { unsigned int w[4]; short8 v; } pa0, pa1, pl0, pl1;
      #pragma unroll
      for (int i = 0; i < 4; ++i) {
        pa0.w[i] = phw[0][(ks << 2) + i];
        pa1.w[i] = phw[1][(ks << 2) + i];
        pl0.w[i] = plw[0][(ks << 2) + i];
        pl1.w[i] = plw[1][(ks << 2) + i];
      }
      #pragma unroll
      for (int jd = 0; jd < 4; ++jd) {
        int vr  = (jd << 4) + l15;                  // d row
        int c0  = ((ks << 2) + (lg >> 1))     ^ (vr & 7);
        int c1  = ((ks << 2) + 2 + (lg >> 1)) ^ (vr & 7);
        int sub = (lg & 1) << 2;                    // u16 sub-offset in chunk
        short8 vh, vl;
        vh.lo = *(const short4v*)(sVh + (vr << 6) + (c0 << 3) + sub);
        vh.hi = *(const short4v*)(sVh + (vr << 6) + (c1 << 3) + sub);
        vl.lo = *(const short4v*)(sVl + (vr << 6) + (c0 << 3) + sub);
        vl.hi = *(const short4v*)(sVl + (vr << 6) + (c1 << 3) + sub);
        ao[0][jd] = MFMA_BF16(pa0.v, vh, ao[0][jd]);
        ao[0][jd] = MFMA_BF16(pa0.v, vl, ao[0][jd]);
        ao[0][jd] = MFMA_BF16(pl0.v, vh, ao[0][jd]);
        ao[1][jd] = MFMA_BF16(pa1.v, vh, ao[1][jd]);
        ao[1][jd] = MFMA_BF16(pa1.v, vl, ao[1][jd]);
        ao[1][jd] = MFMA_BF16(pl1.v, vh, ao[1][jd]);
      }
    }
  }

  // epilogue: O /= l (l broadcast from softmax lanes) ; write split bf16 att
  #pragma unroll
  for (int qf = 0; qf < 2; ++qf)
    #pragma unroll
    for (int r = 0; r < 4; ++r) {
      float lv  = __shfl(lr[qf], (lg << 2) + r);
      float inv = 1.0f / lv;
      size_t orow = ((size_t)((b << 10) + q0 + (w << 5) + (qf << 4) + (lg << 2) + r)) * 1024
                  + (h << 6) + l15;
      #pragma unroll
      for (int jd = 0; jd < 4; ++jd) {
        float v = ao[qf][jd][r] * inv;
        unsigned short hb = f2bf(v);
        oh[orow + (jd << 4)] = hb;
        ol[orow + (jd << 4)] = f2bf(v - bf2f(hb));
      }
    }
}

// ---------------------------------------------------------------------------
// fp32 fallback GEMM
// ---------------------------------------------------------------------------
template <int MODE>
__global__ __launch_bounds__(256)
void gemm_nt(const float* __restrict__ A, const float* __restrict__ Bw,
             const float* __restrict__ b0, const float* __restrict__ b1,
             float* __restrict__ C, int M, int N, int K)
{
  __shared__ float As[32][132];
  __shared__ float Bs[32][132];
  const int tid = threadIdx.x;
  const int tx = tid & 15, ty = tid >> 4;
  const int m0 = blockIdx.y << 7;
  const int n0 = blockIdx.x << 7;

  float acc[8][8];
  #pragma unroll
  for (int i = 0; i < 8; ++i)
    #pragma unroll
    for (int j = 0; j < 8; ++j) acc[i][j] = 0.0f;

  for (int k0 = 0; k0 < K; k0 += 32) {
    #pragma unroll
    for (int u = 0; u < 4; ++u) {
      int f   = tid + (u << 8);
      int row = f >> 3;
      int kk  = (f & 7) << 2;
      float4 av = *(const float4*)(A  + (size_t)(m0 + row) * K + k0 + kk);
      As[kk + 0][row] = av.x; As[kk + 1][row] = av.y;
      As[kk + 2][row] = av.z; As[kk + 3][row] = av.w;
      float4 bv = *(const float4*)(Bw + (size_t)(n0 + row) * K + k0 + kk);
      Bs[kk + 0][row] = bv.x; Bs[kk + 1][row] = bv.y;
      Bs[kk + 2][row] = bv.z; Bs[kk + 3][row] = bv.w;
    }
    __syncthreads();
    #pragma unroll
    for (int kk = 0; kk < 32; ++kk) {
      float a[8], bq[8];
      *(float4*)(a)      = *(const float4*)(&As[kk][(ty << 3)]);
      *(float4*)(a + 4)  = *(const float4*)(&As[kk][(ty << 3) + 4]);
      *(float4*)(bq)     = *(const float4*)(&Bs[kk][(tx << 3)]);
      *(float4*)(bq + 4) = *(const float4*)(&Bs[kk][(tx << 3) + 4]);
      #pragma unroll
      for (int i = 0; i < 8; ++i)
        #pragma unroll
        for (int j = 0; j < 8; ++j)
          acc[i][j] = fmaf(a[i], bq[j], acc[i][j]);
    }
    __syncthreads();
  }

  #pragma unroll
  for (int i = 0; i < 8; ++i) {
    int row = m0 + (ty << 3) + i;
    #pragma unroll
    for (int j4 = 0; j4 < 2; ++j4) {
      int col = n0 + (tx << 3) + (j4 << 2);
      float4 r;
      float bbv[4];
      #pragma unroll
      for (int j = 0; j < 4; ++j)
        bbv[j] = (MODE == 0) ? bias_sel0(b0, b1, col + j) : b0[col + j];
      r.x = acc[i][j4 * 4 + 0] + bbv[0];
      r.y = acc[i][j4 * 4 + 1] + bbv[1];
      r.z = acc[i][j4 * 4 + 2] + bbv[2];
      r.w = acc[i][j4 * 4 + 3] + bbv[3];
      *(float4*)(C + (size_t)row * N + col) = r;
    }
  }
}

// ---------------------------------------------------------------------------
// fp32 in-place qk norm (tiers 2/3)
// ---------------------------------------------------------------------------
__global__ __launch_bounds__(256)
void qk_norm(float* __restrict__ qkv, const float* __restrict__ scale_mul)
{
  int wave = (blockIdx.x << 2) + (threadIdx.x >> 6);
  int lane = threadIdx.x & 63;
  int h  = wave & 15;
  int bl = wave >> 4;
  size_t base = (size_t)bl * 3072 + (h << 6) + lane;
  float q = qkv[base];
  float k = qkv[base + 1024];
  float sq = q * q, sk = k * k;
  #pragma unroll
  for (int off = 32; off; off >>= 1) {
    sq += __shfl_xor(sq, off);
    sk += __shfl_xor(sk, off);
  }
  float sm = __expf(fminf(scale_mul[h], LN100));
  q = q / fmaxf(sqrtf(sq), 1e-12f) * sm;
  k = k / fmaxf(sqrtf(sk), 1e-12f);
  qkv[base]        = q;
  qkv[base + 1024] = k;
}

// ---------------------------------------------------------------------------
// fp32 flash attention (tiers 2/3). OUTMODE 0: fp32 out; 1: split bf16 out.
// ---------------------------------------------------------------------------
#define SW(r, c4) ((((c4) ^ ((r) >> 2)) & 15) << 2)

template <int OUTMODE>
__global__ __launch_bounds__(256)
void attn_fwd(const float* __restrict__ qkv, const float* __restrict__ bias,
              float* __restrict__ aout,
              unsigned short* __restrict__ ah, unsigned short* __restrict__ al)
{
  __shared__ float Qs[64][64];
  __shared__ float Ks[64][64];
  __shared__ float Vs[64][64];
  __shared__ float Ps[64][64];

  const int tid = threadIdx.x;
  const int tx = tid & 15, ty = tid >> 4;
  const int qt = blockIdx.x & 15;
  const int h  = (blockIdx.x >> 4) & 15;
  const int b  = blockIdx.x >> 8;
  const int q0 = qt << 6;

  #pragma unroll
  for (int u = 0; u < 4; ++u) {
    int f = tid + (u << 8);
    int r = f >> 4, c4 = f & 15;
    float4 v = *(const float4*)(qkv + (size_t)(b * 1024 + q0 + r) * 3072 + (h << 6) + (c4 << 2));
    *(float4*)(&Qs[r][SW(r, c4)]) = v;
  }

  float o[4][4];
  float mr[4], lr[4];
  #pragma unroll
  for (int i = 0; i < 4; ++i) {
    mr[i] = -3.0e38f; lr[i] = 0.0f;
    #pragma unroll
    for (int j = 0; j < 4; ++j) o[i][j] = 0.0f;
  }

  for (int kv0 = 0; kv0 < 1024; kv0 += 64) {
    __syncthreads();
    #pragma unroll
    for (int u = 0; u < 4; ++u) {
      int f = tid + (u << 8);
      int r = f >> 4, c4 = f & 15;
      size_t gb = (size_t)(b * 1024 + kv0 + r) * 3072 + (h << 6) + (c4 << 2);
      *(float4*)(&Ks[r][SW(r, c4)]) = *(const float4*)(qkv + gb + 1024);
      *(float4*)(&Vs[r][SW(r, c4)]) = *(const float4*)(qkv + gb + 2048);
    }
    __syncthreads();

    float s[4][4];
    #pragma unroll
    for (int i = 0; i < 4; ++i)
      #pragma unroll
      for (int j = 0; j < 4; ++j) s[i][j] = 0.0f;

    #pragma unroll 4
    for (int d4 = 0; d4 < 16; ++d4) {
      float4 qv[4], kv[4];
      #pragma unroll
      for (int i = 0; i < 4; ++i)
        qv[i] = *(const float4*)(&Qs[(ty << 2) + i][SW((ty << 2) + i, d4)]);
      #pragma unroll
      for (int j = 0; j < 4; ++j)
        kv[j] = *(const float4*)(&Ks[(tx << 2) + j][SW((tx << 2) + j, d4)]);
      #pragma unroll
      for (int i = 0; i < 4; ++i)
        #pragma unroll
        for (int j = 0; j < 4; ++j)
          s[i][j] += qv[i].x * kv[j].x + qv[i].y * kv[j].y +
                     qv[i].z * kv[j].z + qv[i].w * kv[j].w;
    }

    float p[4][4];
    #pragma unroll
    for (int i = 0; i < 4; ++i) {
      float4 bv = *(const float4*)(bias + (size_t)((h << 10) + q0 + (ty << 2) + i) * 1024
                                        + kv0 + (tx << 2));
      s[i][0] += bv.x; s[i][1] += bv.y; s[i][2] += bv.z; s[i][3] += bv.w;
      float mx = fmaxf(fmaxf(s[i][0], s[i][1]), fmaxf(s[i][2], s[i][3]));
      #pragma unroll
      for (int off = 1; off < 16; off <<= 1) mx = fmaxf(mx, __shfl_xor(mx, off));
      float mn = fmaxf(mr[i], mx);
      float alp = __expf(mr[i] - mn);
      float rs = 0.0f;
      #pragma unroll
      for (int j = 0; j < 4; ++j) { p[i][j] = __expf(s[i][j] - mn); rs += p[i][j]; }
      #pragma unroll
      for (int off = 1; off < 16; off <<= 1) rs += __shfl_xor(rs, off);
      lr[i] = lr[i] * alp + rs;
      mr[i] = mn;
      #pragma unroll
      for (int j = 0; j < 4; ++j) o[i][j] *= alp;
    }

    #pragma unroll
    for (int jj = 0; jj < 4; ++jj)
      #pragma unroll
      for (int i = 0; i < 4; ++i)
        Ps[(tx << 2) + jj][SW((tx << 2) + jj, ty) + i] = p[i][jj];
    __syncthreads();

    #pragma unroll 8
    for (int j = 0; j < 64; ++j) {
      float4 pv = *(const float4*)(&Ps[j][SW(j, ty)]);
      float4 vv = *(const float4*)(&Vs[j][SW(j, tx)]);
      o[0][0] += pv.x * vv.x; o[0][1] += pv.x * vv.y; o[0][2] += pv.x * vv.z; o[0][3] += pv.x * vv.w;
      o[1][0] += pv.y * vv.x; o[1][1] += pv.y * vv.y; o[1][2] += pv.y * vv.z; o[1][3] += pv.y * vv.w;
      o[2][0] += pv.z * vv.x; o[2][1] += pv.z * vv.y; o[2][2] += pv.z * vv.z; o[2][3] += pv.z * vv.w;
      o[3][0] += pv.w * vv.x; o[3][1] += pv.w * vv.y; o[3][2] += pv.w * vv.z; o[3][3] += pv.w * vv.w;
    }
  }

  #pragma unroll
  for (int i = 0; i < 4; ++i) {
    float inv = 1.0f / lr[i];
    float v0 = o[i][0] * inv, v1 = o[i][1] * inv, v2 = o[i][2] * inv, v3 = o[i][3] * inv;
    if (OUTMODE == 0) {
      float4 r; r.x = v0; r.y = v1; r.z = v2; r.w = v3;
      *(float4*)(aout + (size_t)(b * 1024 + q0 + (ty << 2) + i) * 1024 + (h << 6) + (tx << 2)) = r;
    } else {
      ushort4 hh, ll;
      hh.x = f2bf(v0); ll.x = f2bf(v0 - bf2f(hh.x));
      hh.y = f2bf(v1); ll.y = f2bf(v1 - bf2f(hh.y));
      hh.z = f2bf(v2); ll.z = f2bf(v2 - bf2f(hh.z));
      hh.w = f2bf(v3); ll.w = f2bf(v3 - bf2f(hh.w));
      size_t idx = (size_t)(b * 1024 + q0 + (ty << 2) + i) * 256 + (h << 4) + tx;
      ((ushort4*)ah)[idx] = hh;
      ((ushort4*)al)[idx] = ll;
    }
  }
}

// ---------------------------------------------------------------------------
extern "C" void kernel_launch(void* const* d_in, const int* in_sizes, int n_in,
                              void* d_out, int out_size, void* d_ws, size_t ws_size,
                              hipStream_t stream) {
  const float* x         = (const float*)d_in[0];
  const float* attn_bias = (const float*)d_in[1];
  const float* w_qkv     = (const float*)d_in[2];
  const float* q_bias    = (const float*)d_in[3];
  const float* v_bias    = (const float*)d_in[4];
  const float* scale_mul = (const float*)d_in[5];
  const float* w_proj    = (const float*)d_in[6];
  const float* b_proj    = (const float*)d_in[7];
  float* out = (float*)d_out;

  const size_t MiB = 1024 * 1024;
  char* ws = (char*)d_ws;
  dim3 blk(256);

  if (ws_size >= 240 * MiB) {
    // ---- tier 1: full MFMA path ----
    float*          qkv = (float*)ws;                         // q/k thirds only
    unsigned short* xh  = (unsigned short*)(ws + 96  * MiB);  // -> att_h
    unsigned short* xl  = (unsigned short*)(ws + 112 * MiB);  // -> att_l
    unsigned short* qkh = (unsigned short*)(ws + 128 * MiB);
    unsigned short* qkl = (unsigned short*)(ws + 160 * MiB);
    unsigned short* vth = (unsigned short*)(ws + 192 * MiB);
    unsigned short* vtl = (unsigned short*)(ws + 208 * MiB);
    unsigned short* wqh = (unsigned short*)(ws + 224 * MiB);
    unsigned short* wql = (unsigned short*)(ws + 230 * MiB);
    unsigned short* wph = (unsigned short*)(ws + 236 * MiB);
    unsigned short* wpl = (unsigned short*)(ws + 238 * MiB);

    split_f32_bf16<<<dim3(8192), blk, 0, stream>>>(x,      xh,  xl,  2097152);
    split_f32_bf16<<<dim3(3072), blk, 0, stream>>>(w_qkv,  wqh, wql, 786432);
    split_f32_bf16<<<dim3(1024), blk, 0, stream>>>(w_proj, wph, wpl, 262144);

    gemm_nt_split<0><<<dim3(24, 64), blk, 0, stream>>>(xh, xl, wqh, wql,
        q_bias, v_bias, qkv, vth, vtl, 8192, 3072, 1024);
    qk_norm_split<<<dim3(32768), blk, 0, stream>>>(qkv, scale_mul, qkh, qkl);
    attn_mfma<<<dim3(1024), blk, 0, stream>>>(qkh, qkl, vth, vtl, attn_bias, xh, xl);
    gemm_nt_split<1><<<dim3(8, 64), blk, 0, stream>>>(xh, xl, wph, wpl,
        b_proj, nullptr, out, nullptr, nullptr, 8192, 1024, 1024);
  } else if (ws_size >= 144 * MiB) {
    // ---- tier 2: MFMA GEMMs + fp32 attention ----
    float*          qkv = (float*)ws;
    unsigned short* xh  = (unsigned short*)(ws + 96  * MiB);
    unsigned short* xl  = (unsigned short*)(ws + 112 * MiB);
    unsigned short* wqh = (unsigned short*)(ws + 128 * MiB);
    unsigned short* wql = (unsigned short*)(ws + 134 * MiB);
    unsigned short* wph = (unsigned short*)(ws + 140 * MiB);
    unsigned short* wpl = (unsigned short*)(ws + 142 * MiB);

    split_f32_bf16<<<dim3(8192), blk, 0, stream>>>(x,      xh,  xl,  2097152);
    split_f32_bf16<<<dim3(3072), blk, 0, stream>>>(w_qkv,  wqh, wql, 786432);
    split_f32_bf16<<<dim3(1024), blk, 0, stream>>>(w_proj, wph, wpl, 262144);

    gemm_nt_split<2><<<dim3(24, 64), blk, 0, stream>>>(xh, xl, wqh, wql,
        q_bias, v_bias, qkv, nullptr, nullptr, 8192, 3072, 1024);
    qk_norm<<<dim3(32768), blk, 0, stream>>>(qkv, scale_mul);
    attn_fwd<1><<<dim3(2048), blk, 0, stream>>>(qkv, attn_bias, nullptr, xh, xl);
    gemm_nt_split<1><<<dim3(8, 64), blk, 0, stream>>>(xh, xl, wph, wpl,
        b_proj, nullptr, out, nullptr, nullptr, 8192, 1024, 1024);
  } else {
    // ---- tier 3: pure fp32 ----
    float* qkv = (float*)ws;
    float* att = qkv + (size_t)8192 * 3072;
    gemm_nt<0><<<dim3(24, 64), blk, 0, stream>>>(x, w_qkv, q_bias, v_bias, qkv, 8192, 3072, 1024);
    qk_norm<<<dim3(32768), blk, 0, stream>>>(qkv, scale_mul);
    attn_fwd<0><<<dim3(2048), blk, 0, stream>>>(qkv, attn_bias, att, nullptr, nullptr);
    gemm_nt<1><<<dim3(8, 64), blk, 0, stream>>>(att, w_proj, b_proj, nullptr, out, 8192, 1024, 1024);
  }
}

// Round 8
// 539.095 us; speedup vs baseline: 1.2037x; 1.0034x over previous
//
#include <hip/hip_runtime.h>
#include <hip/hip_bf16.h>

// ---------------------------------------------------------------------------
// SelfAttention fused pipeline — round 8 (round-7 resubmit after GPU timeout).
//   B=8, L=1024, C=1024, H=16, D=64
// Tier 1 (ws >= 240 MiB): split-bf16 MFMA GEMMs + swapped-operand MFMA flash
//   attention: sequential qf (no spills), bias seeds MFMA C,
//   V stored column-permuted so PV B-operand is one ds_read_b128.
// Tier 2 (ws >= 144 MiB): split-bf16 MFMA GEMMs + fp32 flash attn.
// Tier 3 (else, needs 128 MiB): pure fp32 path.
// ---------------------------------------------------------------------------

#define LN100 4.6051701859880914f

typedef __attribute__((ext_vector_type(8))) short short8;
typedef __attribute__((ext_vector_type(4))) float f32x4;
typedef __attribute__((ext_vector_type(4))) unsigned int u32x4;

#define MFMA_BF16(a, b, c) __builtin_amdgcn_mfma_f32_16x16x32_bf16(a, b, c, 0, 0, 0)

__device__ __forceinline__ unsigned short f2bf(float f) {
  unsigned u = __float_as_uint(f);
  u += 0x7fffu + ((u >> 16) & 1u);          // RNE (no NaNs in this workload)
  return (unsigned short)(u >> 16);
}
__device__ __forceinline__ float bf2f(unsigned short h) {
  return __uint_as_float(((unsigned)h) << 16);
}
// pack two f32 -> u32 of {bf16(a) lo, bf16(b) hi}, RNE (v_cvt_pk path)
__device__ __forceinline__ unsigned int pkbf2(float a, float b) {
  union { __hip_bfloat162 t; unsigned int u; } c;
  c.t = __float22bfloat162_rn(make_float2(a, b));
  return c.u;
}

__device__ __forceinline__ float bias_sel0(const float* qb, const float* vb, int col) {
  if (col < 1024) return qb[col];
  if (col < 2048) return 0.0f;
  return vb[col - 2048];
}

#define G2L16(gp, lp) __builtin_amdgcn_global_load_lds( \
    (const __attribute__((address_space(1))) void*)(gp), \
    (__attribute__((address_space(3))) void*)(lp), 16, 0, 0)

// ---------------------------------------------------------------------------
// split fp32 -> (hi, lo) bf16 pair, 4 elems/thread
// ---------------------------------------------------------------------------
__global__ __launch_bounds__(256)
void split_f32_bf16(const float* __restrict__ in, unsigned short* __restrict__ hi,
                    unsigned short* __restrict__ lo, int n4)
{
  int i = blockIdx.x * blockDim.x + threadIdx.x;
  if (i >= n4) return;
  float4 v = ((const float4*)in)[i];
  ushort4 h, l;
  h.x = f2bf(v.x); l.x = f2bf(v.x - bf2f(h.x));
  h.y = f2bf(v.y); l.y = f2bf(v.y - bf2f(h.y));
  h.z = f2bf(v.z); l.z = f2bf(v.z - bf2f(h.z));
  h.w = f2bf(v.w); l.w = f2bf(v.w - bf2f(h.w));
  ((ushort4*)hi)[i] = h;
  ((ushort4*)lo)[i] = l;
}

// ---------------------------------------------------------------------------
// Split-bf16 MFMA GEMM. MODE 0: qkv GEMM tier-1 (q/k -> fp32 C; V cols ->
// vth/vtl direct, transposed AND column-permuted: within each 32-kv block,
// storage col c = (kv&3) + ((kv>>4)&1)*4 + ((kv>>2)&3)*8, +32*(kv>>5)).
// MODE 1: proj GEMM. MODE 2: qkv GEMM plain fp32 (tier 2).
// ---------------------------------------------------------------------------
template <int MODE>
__global__ __launch_bounds__(256)
void gemm_nt_split(const unsigned short* __restrict__ Ah, const unsigned short* __restrict__ Al,
                   const unsigned short* __restrict__ Wh, const unsigned short* __restrict__ Wl,
                   const float* __restrict__ b0, const float* __restrict__ b1,
                   float* __restrict__ C,
                   unsigned short* __restrict__ vth, unsigned short* __restrict__ vtl,
                   int M, int N, int K)
{
  __shared__ unsigned short sA[128 * 64];
  __shared__ unsigned short sW[128 * 64];

  const int tid  = threadIdx.x;
  const int lane = tid & 63;
  const int l15  = lane & 15, lg = lane >> 4;
  const int w    = tid >> 6;
  const int wr   = (w >> 1) << 6;
  const int wc   = (w & 1) << 6;
  const int m0   = blockIdx.y << 7;
  const int n0   = blockIdx.x << 7;

  f32x4 acc[4][4];
  #pragma unroll
  for (int i = 0; i < 4; ++i)
    #pragma unroll
    for (int j = 0; j < 4; ++j)
      acc[i][j] = (f32x4){0.f, 0.f, 0.f, 0.f};

  for (int k0 = 0; k0 < K; k0 += 32) {
    __syncthreads();
    #pragma unroll
    for (int u = 0; u < 4; ++u) {
      int idx = (u << 8) + tid;
      int row = idx >> 3;
      int c   = idx & 7;
      int s   = c ^ (row & 7);
      size_t rbA = (size_t)(m0 + row) * K + k0;
      size_t rbW = (size_t)(n0 + row) * K + k0;
      const unsigned short* srcA = (s < 4) ? (Ah + rbA + (s << 3))
                                           : (Al + rbA + ((s - 4) << 3));
      const unsigned short* srcW = (s < 4) ? (Wh + rbW + (s << 3))
                                           : (Wl + rbW + ((s - 4) << 3));
      G2L16(srcA, sA + (idx << 3));
      G2L16(srcW, sW + (idx << 3));
    }
    __syncthreads();

    short8 ah[4], al[4];
    #pragma unroll
    for (int i = 0; i < 4; ++i) {
      int row = wr + (i << 4) + l15;
      ah[i] = *(const short8*)(sA + (row << 6) + ((lg       ^ (row & 7)) << 3));
      al[i] = *(const short8*)(sA + (row << 6) + (((4 + lg) ^ (row & 7)) << 3));
    }
    #pragma unroll
    for (int j = 0; j < 4; ++j) {
      int row = wc + (j << 4) + l15;
      short8 wh = *(const short8*)(sW + (row << 6) + ((lg       ^ (row & 7)) << 3));
      short8 wl = *(const short8*)(sW + (row << 6) + (((4 + lg) ^ (row & 7)) << 3));
      #pragma unroll
      for (int i = 0; i < 4; ++i) {
        acc[i][j] = MFMA_BF16(ah[i], wh, acc[i][j]);
        acc[i][j] = MFMA_BF16(ah[i], wl, acc[i][j]);
        acc[i][j] = MFMA_BF16(al[i], wh, acc[i][j]);
      }
    }
  }

  if (MODE == 0 && n0 >= 2048) {
    // V third: transposed + column-permuted split bf16
    #pragma unroll
    for (int j = 0; j < 4; ++j) {
      int col = n0 + wc + (j << 4) + l15;
      int d   = col - 2048;
      int hh  = d >> 6, dd = d & 63;
      float bb = b1[d];
      #pragma unroll
      for (int i = 0; i < 4; ++i) {
        int row  = m0 + wr + (i << 4) + (lg << 2);   // kv rows row..row+3
        int bidx = row >> 10;
        int l    = row & 1023;
        // permuted storage col base for kv = l..l+3 (l % 4 == 0)
        int cbase = (((l >> 4) & 1) << 2) + (((l >> 2) & 3) << 3) + ((l >> 5) << 5);
        size_t obase = ((((size_t)bidx << 4) + hh) << 6) + dd;
        obase = obase * 1024 + cbase;
        ushort4 hv, lv;
        float v0 = acc[i][j][0] + bb;
        float v1 = acc[i][j][1] + bb;
        float v2 = acc[i][j][2] + bb;
        float v3 = acc[i][j][3] + bb;
        hv.x = f2bf(v0); lv.x = f2bf(v0 - bf2f(hv.x));
        hv.y = f2bf(v1); lv.y = f2bf(v1 - bf2f(hv.y));
        hv.z = f2bf(v2); lv.z = f2bf(v2 - bf2f(hv.z));
        hv.w = f2bf(v3); lv.w = f2bf(v3 - bf2f(hv.w));
        *(ushort4*)(vth + obase) = hv;
        *(ushort4*)(vtl + obase) = lv;
      }
    }
  } else {
    #pragma unroll
    for (int j = 0; j < 4; ++j) {
      int col = n0 + wc + (j << 4) + l15;
      float bb = (MODE == 1) ? b0[col] : bias_sel0(b0, b1, col);
      #pragma unroll
      for (int i = 0; i < 4; ++i) {
        int rbase = m0 + wr + (i << 4) + (lg << 2);
        #pragma unroll
        for (int r = 0; r < 4; ++r)
          C[(size_t)(rbase + r) * N + col] = acc[i][j][r] + bb;
      }
    }
  }
}

// ---------------------------------------------------------------------------
// l2norm q,k -> split bf16 arrays qk_h/qk_l [8192][2048] (q | k), tier 1.
// ---------------------------------------------------------------------------
__global__ __launch_bounds__(256)
void qk_norm_split(const float* __restrict__ qkv, const float* __restrict__ scale_mul,
                   unsigned short* __restrict__ qk_h, unsigned short* __restrict__ qk_l)
{
  int wave = (blockIdx.x << 2) + (threadIdx.x >> 6);
  int lane = threadIdx.x & 63;
  int h  = wave & 15;
  int bl = wave >> 4;
  size_t base = (size_t)bl * 3072 + (h << 6) + lane;
  float q = qkv[base];
  float k = qkv[base + 1024];
  float sq = q * q, sk = k * k;
  #pragma unroll
  for (int off = 32; off; off >>= 1) {
    sq += __shfl_xor(sq, off);
    sk += __shfl_xor(sk, off);
  }
  float sm = __expf(fminf(scale_mul[h], LN100));
  q = q / fmaxf(sqrtf(sq), 1e-12f) * sm;
  k = k / fmaxf(sqrtf(sk), 1e-12f);
  size_t ob = (size_t)bl * 2048 + (h << 6) + lane;
  unsigned short qh = f2bf(q);
  qk_h[ob] = qh;          qk_l[ob] = f2bf(q - bf2f(qh));
  unsigned short kh = f2bf(k);
  qk_h[ob + 1024] = kh;   qk_l[ob + 1024] = f2bf(k - bf2f(kh));
}

// ---------------------------------------------------------------------------
// Swapped-operand split-bf16 MFMA flash attention, QBLK=128, KVBLK=64.
// Block = (b,h,128 q-rows), 4 waves; wave w owns q rows 32w..32w+31 as two
// 16-row fragments qf, processed FULLY SEQUENTIALLY (register pressure).
// S^T = mfma(A=K, B=Q) with C seeded by the attention bias (free add).
// C/D: col(l15)=q, row(lg*4+r+16j)=kv -> lane holds a 64-wide P-row slice.
// Softmax: lane-local over 16 regs + xor16/xor32; alpha -> O-layout via shfl.
// PV: A = P packed in-register; B = permuted V^T, ONE ds_read_b128 per
// (ks,jd) (slot order matches pack order by construction). No P LDS.
// ---------------------------------------------------------------------------
__global__ __launch_bounds__(256, 2)
void attn_mfma(const unsigned short* __restrict__ qk_h, const unsigned short* __restrict__ qk_l,
               const unsigned short* __restrict__ vth, const unsigned short* __restrict__ vtl,
               const float* __restrict__ bias,
               unsigned short* __restrict__ oh, unsigned short* __restrict__ ol)
{
  __shared__ unsigned short sKh[4096], sKl[4096];    // 64 kv rows x 64 u16
  __shared__ unsigned short sVh[4096], sVl[4096];    // 64 d rows x 64 u16 (perm cols)

  const int tid  = threadIdx.x;
  const int lane = tid & 63;
  const int l15  = lane & 15, lg = lane >> 4;
  const int w    = tid >> 6;
  const int qt = blockIdx.x & 7;
  const int h  = (blockIdx.x >> 3) & 15;
  const int b  = blockIdx.x >> 7;
  const int q0 = qt << 7;

  // Q fragments (B-operand): lane l15 = q-row, chunk lg*8 + ks*32 over d
  short8 qh[2][2], qlo[2][2];
  #pragma unroll
  for (int qf = 0; qf < 2; ++qf) {
    size_t rb = ((size_t)((b << 10) + q0 + (w << 5) + (qf << 4) + l15)) * 2048
              + (h << 6) + (lg << 3);
    qh[qf][0]  = *(const short8*)(qk_h + rb);
    qh[qf][1]  = *(const short8*)(qk_h + rb + 32);
    qlo[qf][0] = *(const short8*)(qk_l + rb);
    qlo[qf][1] = *(const short8*)(qk_l + rb + 32);
  }

  f32x4 ao[2][4];            // [qf][jd] O: row q=lg*4+r, col d=jd*16+l15
  float mr[2], lr[2];        // per qf, this lane's q-row = l15
  #pragma unroll
  for (int qf = 0; qf < 2; ++qf) {
    #pragma unroll
    for (int j = 0; j < 4; ++j) ao[qf][j] = (f32x4){0.f, 0.f, 0.f, 0.f};
    mr[qf] = -3.0e38f; lr[qf] = 0.0f;
  }

  const unsigned short* kh_base = qk_h + 1024 + (h << 6);
  const unsigned short* kl_base = qk_l + 1024 + (h << 6);
  const size_t vbase = ((size_t)((b << 4) + h)) * 65536;
  const float* bias_base = bias + ((size_t)h << 20)
                         + (size_t)(q0 + (w << 5) + l15) * 1024 + (lg << 2);

  for (int kv0 = 0; kv0 < 1024; kv0 += 64) {
    __syncthreads();
    // ---- stage K (64x64) and perm-V^T (64x64), hi/lo, swizzled ----
    #pragma unroll
    for (int u = 0; u < 2; ++u) {
      int idx = (u << 8) + tid;        // 0..511
      int r = idx >> 3, c = idx & 7;
      int s = c ^ (r & 7);
      size_t krow = (size_t)((b << 10) + kv0 + r) * 2048 + (s << 3);
      size_t vrow = vbase + (size_t)r * 1024 + kv0 + (s << 3);
      G2L16(kh_base + krow, sKh + (idx << 3));
      G2L16(kl_base + krow, sKl + (idx << 3));
      G2L16(vth + vrow,     sVh + (idx << 3));
      G2L16(vtl + vrow,     sVl + (idx << 3));
    }
    __syncthreads();

    #pragma unroll
    for (int qf = 0; qf < 2; ++qf) {
      // ---- S^T = K.Q + bias (bias seeds the MFMA accumulator) ----
      f32x4 sv[4];
      #pragma unroll
      for (int j = 0; j < 4; ++j) {
        float4 bv = *(const float4*)(bias_base + (size_t)(qf << 4) * 1024
                                     + kv0 + (j << 4));
        f32x4 a = (f32x4){bv.x, bv.y, bv.z, bv.w};
        int row = (j << 4) + l15;                 // kv row in tile
        int c0 = lg ^ (row & 7);
        int c1 = (lg + 4) ^ (row & 7);
        short8 kh0 = *(const short8*)(sKh + (row << 6) + (c0 << 3));
        short8 kl0 = *(const short8*)(sKl + (row << 6) + (c0 << 3));
        short8 kh1 = *(const short8*)(sKh + (row << 6) + (c1 << 3));
        short8 kl1 = *(const short8*)(sKl + (row << 6) + (c1 << 3));
        a = MFMA_BF16(kh0, qh[qf][0], a);
        a = MFMA_BF16(kl0, qh[qf][0], a);
        a = MFMA_BF16(kh0, qlo[qf][0], a);
        a = MFMA_BF16(kh1, qh[qf][1], a);
        a = MFMA_BF16(kl1, qh[qf][1], a);
        a = MFMA_BF16(kh1, qlo[qf][1], a);
        sv[j] = a;
      }

      // ---- softmax (lane-local 16 + xor16/xor32) ----
      float mx = -3.0e38f;
      #pragma unroll
      for (int j = 0; j < 4; ++j)
        #pragma unroll
        for (int r = 0; r < 4; ++r) mx = fmaxf(mx, sv[j][r]);
      mx = fmaxf(mx, __shfl_xor(mx, 16));
      mx = fmaxf(mx, __shfl_xor(mx, 32));
      float mn = fmaxf(mr[qf], mx);
      float al = __expf(mr[qf] - mn);
      mr[qf] = mn;
      float rs = 0.0f;
      #pragma unroll
      for (int j = 0; j < 4; ++j)
        #pragma unroll
        for (int r = 0; r < 4; ++r) {
          float e = __expf(sv[j][r] - mn);
          sv[j][r] = e;
          rs += e;
        }
      rs += __shfl_xor(rs, 16);
      rs += __shfl_xor(rs, 32);
      lr[qf] = lr[qf] * al + rs;
      // alpha -> O layout (q = lg*4+r) and rescale
      #pragma unroll
      for (int r = 0; r < 4; ++r) {
        float av = __shfl(al, (lg << 2) + r);
        #pragma unroll
        for (int jd = 0; jd < 4; ++jd) ao[qf][jd][r] *= av;
      }

      // ---- pack P per ks and accumulate O += P.V ----
      #pragma unroll
      for (int ks = 0; ks < 2; ++ks) {
        unsigned int h0 = pkbf2(sv[2*ks][0],     sv[2*ks][1]);
        unsigned int h1 = pkbf2(sv[2*ks][2],     sv[2*ks][3]);
        unsigned int h2 = pkbf2(sv[2*ks + 1][0], sv[2*ks + 1][1]);
        unsigned int h3 = pkbf2(sv[2*ks + 1][2], sv[2*ks + 1][3]);
        unsigned int l0 = pkbf2(sv[2*ks][0]     - __uint_as_float(h0 << 16),
                                sv[2*ks][1]     - __uint_as_float(h0 & 0xffff0000u));
        unsigned int l1 = pkbf2(sv[2*ks][2]     - __uint_as_float(h1 << 16),
                                sv[2*ks][3]     - __uint_as_float(h1 & 0xffff0000u));
        unsigned int l2 = pkbf2(sv[2*ks + 1][0] - __uint_as_float(h2 << 16),
                                sv[2*ks + 1][1] - __uint_as_float(h2 & 0xffff0000u));
        unsigned int l3 = pkbf2(sv[2*ks + 1][2] - __uint_as_float(h3 << 16),
                                sv[2*ks + 1][3] - __uint_as_float(h3 & 0xffff0000u));
        union { u32x4 u; short8 s; } ph, pl;
        ph.u = (u32x4){h0, h1, h2, h3};
        pl.u = (u32x4){l0, l1, l2, l3};
        #pragma unroll
        for (int jd = 0; jd < 4; ++jd) {
          int vr = (jd << 4) + l15;               // d row (perm cols)
          int c  = ((ks << 2) + lg) ^ (vr & 7);
          short8 vh = *(const short8*)(sVh + (vr << 6) + (c << 3));
          short8 vl = *(const short8*)(sVl + (vr << 6) + (c << 3));
          ao[qf][jd] = MFMA_BF16(ph.s, vh, ao[qf][jd]);
          ao[qf][jd] = MFMA_BF16(ph.s, vl, ao[qf][jd]);
          ao[qf][jd] = MFMA_BF16(pl.s, vh, ao[qf][jd]);
        }
      }
    }
  }

  // epilogue: O /= l (broadcast l to O layout) ; write split bf16 att
  #pragma unroll
  for (int qf = 0; qf < 2; ++qf)
    #pragma unroll
    for (int r = 0; r < 4; ++r) {
      float lv  = __shfl(lr[qf], (lg << 2) + r);
      float inv = 1.0f / lv;
      size_t orow = ((size_t)((b << 10) + q0 + (w << 5) + (qf << 4) + (lg << 2) + r)) * 1024
                  + (h << 6) + l15;
      #pragma unroll
      for (int jd = 0; jd < 4; ++jd) {
        float v = ao[qf][jd][r] * inv;
        unsigned short hb = f2bf(v);
        oh[orow + (jd << 4)] = hb;
        ol[orow + (jd << 4)] = f2bf(v - bf2f(hb));
      }
    }
}

// ---------------------------------------------------------------------------
// fp32 fallback GEMM
// ---------------------------------------------------------------------------
template <int MODE>
__global__ __launch_bounds__(256)
void gemm_nt(const float* __restrict__ A, const float* __restrict__ Bw,
             const float* __restrict__ b0, const float* __restrict__ b1,
             float* __restrict__ C, int M, int N, int K)
{
  __shared__ float As[32][132];
  __shared__ float Bs[32][132];
  const int tid = threadIdx.x;
  const int tx = tid & 15, ty = tid >> 4;
  const int m0 = blockIdx.y << 7;
  const int n0 = blockIdx.x << 7;

  float acc[8][8];
  #pragma unroll
  for (int i = 0; i < 8; ++i)
    #pragma unroll
    for (int j = 0; j < 8; ++j) acc[i][j] = 0.0f;

  for (int k0 = 0; k0 < K; k0 += 32) {
    #pragma unroll
    for (int u = 0; u < 4; ++u) {
      int f   = tid + (u << 8);
      int row = f >> 3;
      int kk  = (f & 7) << 2;
      float4 av = *(const float4*)(A  + (size_t)(m0 + row) * K + k0 + kk);
      As[kk + 0][row] = av.x; As[kk + 1][row] = av.y;
      As[kk + 2][row] = av.z; As[kk + 3][row] = av.w;
      float4 bv = *(const float4*)(Bw + (size_t)(n0 + row) * K + k0 + kk);
      Bs[kk + 0][row] = bv.x; Bs[kk + 1][row] = bv.y;
      Bs[kk + 2][row] = bv.z; Bs[kk + 3][row] = bv.w;
    }
    __syncthreads();
    #pragma unroll
    for (int kk = 0; kk < 32; ++kk) {
      float a[8], bq[8];
      *(float4*)(a)      = *(const float4*)(&As[kk][(ty << 3)]);
      *(float4*)(a + 4)  = *(const float4*)(&As[kk][(ty << 3) + 4]);
      *(float4*)(bq)     = *(const float4*)(&Bs[kk][(tx << 3)]);
      *(float4*)(bq + 4) = *(const float4*)(&Bs[kk][(tx << 3) + 4]);
      #pragma unroll
      for (int i = 0; i < 8; ++i)
        #pragma unroll
        for (int j = 0; j < 8; ++j)
          acc[i][j] = fmaf(a[i], bq[j], acc[i][j]);
    }
    __syncthreads();
  }

  #pragma unroll
  for (int i = 0; i < 8; ++i) {
    int row = m0 + (ty << 3) + i;
    #pragma unroll
    for (int j4 = 0; j4 < 2; ++j4) {
      int col = n0 + (tx << 3) + (j4 << 2);
      float4 r;
      float bbv[4];
      #pragma unroll
      for (int j = 0; j < 4; ++j)
        bbv[j] = (MODE == 0) ? bias_sel0(b0, b1, col + j) : b0[col + j];
      r.x = acc[i][j4 * 4 + 0] + bbv[0];
      r.y = acc[i][j4 * 4 + 1] + bbv[1];
      r.z = acc[i][j4 * 4 + 2] + bbv[2];
      r.w = acc[i][j4 * 4 + 3] + bbv[3];
      *(float4*)(C + (size_t)row * N + col) = r;
    }
  }
}

// ---------------------------------------------------------------------------
// fp32 in-place qk norm (tiers 2/3)
// ---------------------------------------------------------------------------
__global__ __launch_bounds__(256)
void qk_norm(float* __restrict__ qkv, const float* __restrict__ scale_mul)
{
  int wave = (blockIdx.x << 2) + (threadIdx.x >> 6);
  int lane = threadIdx.x & 63;
  int h  = wave & 15;
  int bl = wave >> 4;
  size_t base = (size_t)bl * 3072 + (h << 6) + lane;
  float q = qkv[base];
  float k = qkv[base + 1024];
  float sq = q * q, sk = k * k;
  #pragma unroll
  for (int off = 32; off; off >>= 1) {
    sq += __shfl_xor(sq, off);
    sk += __shfl_xor(sk, off);
  }
  float sm = __expf(fminf(scale_mul[h], LN100));
  q = q / fmaxf(sqrtf(sq), 1e-12f) * sm;
  k = k / fmaxf(sqrtf(sk), 1e-12f);
  qkv[base]        = q;
  qkv[base + 1024] = k;
}

// ---------------------------------------------------------------------------
// fp32 flash attention (tiers 2/3). OUTMODE 0: fp32 out; 1: split bf16 out.
// ---------------------------------------------------------------------------
#define SW(r, c4) ((((c4) ^ ((r) >> 2)) & 15) << 2)

template <int OUTMODE>
__global__ __launch_bounds__(256)
void attn_fwd(const float* __restrict__ qkv, const float* __restrict__ bias,
              float* __restrict__ aout,
              unsigned short* __restrict__ ah, unsigned short* __restrict__ al)
{
  __shared__ float Qs[64][64];
  __shared__ float Ks[64][64];
  __shared__ float Vs[64][64];
  __shared__ float Ps[64][64];

  const int tid = threadIdx.x;
  const int tx = tid & 15, ty = tid >> 4;
  const int qt = blockIdx.x & 15;
  const int h  = (blockIdx.x >> 4) & 15;
  const int b  = blockIdx.x >> 8;
  const int q0 = qt << 6;

  #pragma unroll
  for (int u = 0; u < 4; ++u) {
    int f = tid + (u << 8);
    int r = f >> 4, c4 = f & 15;
    float4 v = *(const float4*)(qkv + (size_t)(b * 1024 + q0 + r) * 3072 + (h << 6) + (c4 << 2));
    *(float4*)(&Qs[r][SW(r, c4)]) = v;
  }

  float o[4][4];
  float mr[4], lr[4];
  #pragma unroll
  for (int i = 0; i < 4; ++i) {
    mr[i] = -3.0e38f; lr[i] = 0.0f;
    #pragma unroll
    for (int j = 0; j < 4; ++j) o[i][j] = 0.0f;
  }

  for (int kv0 = 0; kv0 < 1024; kv0 += 64) {
    __syncthreads();
    #pragma unroll
    for (int u = 0; u < 4; ++u) {
      int f = tid + (u << 8);
      int r = f >> 4, c4 = f & 15;
      size_t gb = (size_t)(b * 1024 + kv0 + r) * 3072 + (h << 6) + (c4 << 2);
      *(float4*)(&Ks[r][SW(r, c4)]) = *(const float4*)(qkv + gb + 1024);
      *(float4*)(&Vs[r][SW(r, c4)]) = *(const float4*)(qkv + gb + 2048);
    }
    __syncthreads();

    float s[4][4];
    #pragma unroll
    for (int i = 0; i < 4; ++i)
      #pragma unroll
      for (int j = 0; j < 4; ++j) s[i][j] = 0.0f;

    #pragma unroll 4
    for (int d4 = 0; d4 < 16; ++d4) {
      float4 qv[4], kv[4];
      #pragma unroll
      for (int i = 0; i < 4; ++i)
        qv[i] = *(const float4*)(&Qs[(ty << 2) + i][SW((ty << 2) + i, d4)]);
      #pragma unroll
      for (int j = 0; j < 4; ++j)
        kv[j] = *(const float4*)(&Ks[(tx << 2) + j][SW((tx << 2) + j, d4)]);
      #pragma unroll
      for (int i = 0; i < 4; ++i)
        #pragma unroll
        for (int j = 0; j < 4; ++j)
          s[i][j] += qv[i].x * kv[j].x + qv[i].y * kv[j].y +
                     qv[i].z * kv[j].z + qv[i].w * kv[j].w;
    }

    float p[4][4];
    #pragma unroll
    for (int i = 0; i < 4; ++i) {
      float4 bv = *(const float4*)(bias + (size_t)((h << 10) + q0 + (ty << 2) + i) * 1024
                                        + kv0 + (tx << 2));
      s[i][0] += bv.x; s[i][1] += bv.y; s[i][2] += bv.z; s[i][3] += bv.w;
      float mx = fmaxf(fmaxf(s[i][0], s[i][1]), fmaxf(s[i][2], s[i][3]));
      #pragma unroll
      for (int off = 1; off < 16; off <<= 1) mx = fmaxf(mx, __shfl_xor(mx, off));
      float mn = fmaxf(mr[i], mx);
      float alp = __expf(mr[i] - mn);
      float rs = 0.0f;
      #pragma unroll
      for (int j = 0; j < 4; ++j) { p[i][j] = __expf(s[i][j] - mn); rs += p[i][j]; }
      #pragma unroll
      for (int off = 1; off < 16; off <<= 1) rs += __shfl_xor(rs, off);
      lr[i] = lr[i] * alp + rs;
      mr[i] = mn;
      #pragma unroll
      for (int j = 0; j < 4; ++j) o[i][j] *= alp;
    }

    #pragma unroll
    for (int jj = 0; jj < 4; ++jj)
      #pragma unroll
      for (int i = 0; i < 4; ++i)
        Ps[(tx << 2) + jj][SW((tx << 2) + jj, ty) + i] = p[i][jj];
    __syncthreads();

    #pragma unroll 8
    for (int j = 0; j < 64; ++j) {
      float4 pv = *(const float4*)(&Ps[j][SW(j, ty)]);
      float4 vv = *(const float4*)(&Vs[j][SW(j, tx)]);
      o[0][0] += pv.x * vv.x; o[0][1] += pv.x * vv.y; o[0][2] += pv.x * vv.z; o[0][3] += pv.x * vv.w;
      o[1][0] += pv.y * vv.x; o[1][1] += pv.y * vv.y; o[1][2] += pv.y * vv.z; o[1][3] += pv.y * vv.w;
      o[2][0] += pv.z * vv.x; o[2][1] += pv.z * vv.y; o[2][2] += pv.z * vv.z; o[2][3] += pv.z * vv.w;
      o[3][0] += pv.w * vv.x; o[3][1] += pv.w * vv.y; o[3][2] += pv.w * vv.z; o[3][3] += pv.w * vv.w;
    }
  }

  #pragma unroll
  for (int i = 0; i < 4; ++i) {
    float inv = 1.0f / lr[i];
    float v0 = o[i][0] * inv, v1 = o[i][1] * inv, v2 = o[i][2] * inv, v3 = o[i][3] * inv;
    if (OUTMODE == 0) {
      float4 r; r.x = v0; r.y = v1; r.z = v2; r.w = v3;
      *(float4*)(aout + (size_t)(b * 1024 + q0 + (ty << 2) + i) * 1024 + (h << 6) + (tx << 2)) = r;
    } else {
      ushort4 hh, ll;
      hh.x = f2bf(v0); ll.x = f2bf(v0 - bf2f(hh.x));
      hh.y = f2bf(v1); ll.y = f2bf(v1 - bf2f(hh.y));
      hh.z = f2bf(v2); ll.z = f2bf(v2 - bf2f(hh.z));
      hh.w = f2bf(v3); ll.w = f2bf(v3 - bf2f(hh.w));
      size_t idx = (size_t)(b * 1024 + q0 + (ty << 2) + i) * 256 + (h << 4) + tx;
      ((ushort4*)ah)[idx] = hh;
      ((ushort4*)al)[idx] = ll;
    }
  }
}

// ---------------------------------------------------------------------------
extern "C" void kernel_launch(void* const* d_in, const int* in_sizes, int n_in,
                              void* d_out, int out_size, void* d_ws, size_t ws_size,
                              hipStream_t stream) {
  const float* x         = (const float*)d_in[0];
  const float* attn_bias = (const float*)d_in[1];
  const float* w_qkv     = (const float*)d_in[2];
  const float* q_bias    = (const float*)d_in[3];
  const float* v_bias    = (const float*)d_in[4];
  const float* scale_mul = (const float*)d_in[5];
  const float* w_proj    = (const float*)d_in[6];
  const float* b_proj    = (const float*)d_in[7];
  float* out = (float*)d_out;

  const size_t MiB = 1024 * 1024;
  char* ws = (char*)d_ws;
  dim3 blk(256);

  if (ws_size >= 240 * MiB) {
    // ---- tier 1: full MFMA path ----
    float*          qkv = (float*)ws;                         // q/k thirds only
    unsigned short* xh  = (unsigned short*)(ws + 96  * MiB);  // -> att_h
    unsigned short* xl  = (unsigned short*)(ws + 112 * MiB);  // -> att_l
    unsigned short* qkh = (unsigned short*)(ws + 128 * MiB);
    unsigned short* qkl = (unsigned short*)(ws + 160 * MiB);
    unsigned short* vth = (unsigned short*)(ws + 192 * MiB);
    unsigned short* vtl = (unsigned short*)(ws + 208 * MiB);
    unsigned short* wqh = (unsigned short*)(ws + 224 * MiB);
    unsigned short* wql = (unsigned short*)(ws + 230 * MiB);
    unsigned short* wph = (unsigned short*)(ws + 236 * MiB);
    unsigned short* wpl = (unsigned short*)(ws + 238 * MiB);

    split_f32_bf16<<<dim3(8192), blk, 0, stream>>>(x,      xh,  xl,  2097152);
    split_f32_bf16<<<dim3(3072), blk, 0, stream>>>(w_qkv,  wqh, wql, 786432);
    split_f32_bf16<<<dim3(1024), blk, 0, stream>>>(w_proj, wph, wpl, 262144);

    gemm_nt_split<0><<<dim3(24, 64), blk, 0, stream>>>(xh, xl, wqh, wql,
        q_bias, v_bias, qkv, vth, vtl, 8192, 3072, 1024);
    qk_norm_split<<<dim3(32768), blk, 0, stream>>>(qkv, scale_mul, qkh, qkl);
    attn_mfma<<<dim3(1024), blk, 0, stream>>>(qkh, qkl, vth, vtl, attn_bias, xh, xl);
    gemm_nt_split<1><<<dim3(8, 64), blk, 0, stream>>>(xh, xl, wph, wpl,
        b_proj, nullptr, out, nullptr, nullptr, 8192, 1024, 1024);
  } else if (ws_size >= 144 * MiB) {
    // ---- tier 2: MFMA GEMMs + fp32 attention ----
    float*          qkv = (float*)ws;
    unsigned short* xh  = (unsigned short*)(ws + 96  * MiB);
    unsigned short* xl  = (unsigned short*)(ws + 112 * MiB);
    unsigned short* wqh = (unsigned short*)(ws + 128 * MiB);
    unsigned short* wql = (unsigned short*)(ws + 134 * MiB);
    unsigned short* wph = (unsigned short*)(ws + 140 * MiB);
    unsigned short* wpl = (unsigned short*)(ws + 142 * MiB);

    split_f32_bf16<<<dim3(8192), blk, 0, stream>>>(x,      xh,  xl,  2097152);
    split_f32_bf16<<<dim3(3072), blk, 0, stream>>>(w_qkv,  wqh, wql, 786432);
    split_f32_bf16<<<dim3(1024), blk, 0, stream>>>(w_proj, wph, wpl, 262144);

    gemm_nt_split<2><<<dim3(24, 64), blk, 0, stream>>>(xh, xl, wqh, wql,
        q_bias, v_bias, qkv, nullptr, nullptr, 8192, 3072, 1024);
    qk_norm<<<dim3(32768), blk, 0, stream>>>(qkv, scale_mul);
    attn_fwd<1><<<dim3(2048), blk, 0, stream>>>(qkv, attn_bias, nullptr, xh, xl);
    gemm_nt_split<1><<<dim3(8, 64), blk, 0, stream>>>(xh, xl, wph, wpl,
        b_proj, nullptr, out, nullptr, nullptr, 8192, 1024, 1024);
  } else {
    // ---- tier 3: pure fp32 ----
    float* qkv = (float*)ws;
    float* att = qkv + (size_t)8192 * 3072;
    gemm_nt<0><<<dim3(24, 64), blk, 0, stream>>>(x, w_qkv, q_bias, v_bias, qkv, 8192, 3072, 1024);
    qk_norm<<<dim3(32768), blk, 0, stream>>>(qkv, scale_mul);
    attn_fwd<0><<<dim3(2048), blk, 0, stream>>>(qkv, attn_bias, att, nullptr, nullptr);
    gemm_nt<1><<<dim3(8, 64), blk, 0, stream>>>(att, w_proj, b_proj, nullptr, out, 8192, 1024, 1024);
  }
}